// Round 1
// baseline (2613.299 us; speedup 1.0000x reference)
//
#include <hip/hip_runtime.h>
#include <math.h>

#define P 128
#define NP (P*P)
#define BATCH 4

__device__ __forceinline__ float sigmoidf_(float x){ return 1.f/(1.f+__expf(-x)); }

// ---------------- maxpool 2x2 stride 2: (B,32,256,256) -> (B,32,128,128) ----------------
__global__ void maxpool_k(const float* __restrict__ x, float* __restrict__ xp){
  int idx = blockIdx.x*256 + threadIdx.x;
  const int total = BATCH*32*NP;
  if (idx >= total) return;
  int wp = idx & (P-1); int t = idx >> 7; int hp = t & (P-1); int bc = t >> 7;
  const float* src = x + (((size_t)bc*256) + hp*2)*256 + wp*2;
  float a = src[0], b = src[1], c = src[256], d = src[257];
  xp[idx] = fmaxf(fmaxf(a,b), fmaxf(c,d));
}

// ---------------- direct 3x3 conv, Cin -> 18 offset channels ----------------
template<int CIN>
__global__ void offconv_k(const float* __restrict__ in, const float* __restrict__ w,
                          const float* __restrict__ bias, float* __restrict__ out){
  // block 256 = 16x16 pixels; grid: (64 tiles, B)
  __shared__ float wl[18*CIN*9];
  for (int e = threadIdx.x; e < 18*CIN*9; e += 256) wl[e] = w[e];
  __syncthreads();
  int b = blockIdx.y;
  int tile = blockIdx.x;
  int wx = (tile & 7)*16 + (threadIdx.x & 15);
  int hy = (tile >> 3)*16 + (threadIdx.x >> 4);
  float acc[18];
  #pragma unroll
  for (int o = 0; o < 18; o++) acc[o] = bias[o];
  const float* inb = in + (size_t)b*CIN*NP;
  for (int c = 0; c < CIN; c++){
    const float* inc = inb + c*NP;
    #pragma unroll
    for (int ky = 0; ky < 3; ky++){
      int yy = hy + ky - 1;
      bool yok = ((unsigned)yy < P);
      #pragma unroll
      for (int kx = 0; kx < 3; kx++){
        int xx = wx + kx - 1;
        float v = (yok && (unsigned)xx < P) ? inc[yy*P+xx] : 0.f;
        const float* wp_ = &wl[c*9 + ky*3 + kx];
        #pragma unroll
        for (int o = 0; o < 18; o++) acc[o] = fmaf(v, wp_[o*CIN*9], acc[o]);
      }
    }
  }
  float* ob = out + (size_t)b*18*NP + hy*P + wx;
  #pragma unroll
  for (int o = 0; o < 18; o++) ob[o*NP] = acc[o];
}

// ---------------- deformable sample + einsum: (B,CIN,P,P)+(B,18,P,P) -> (B,64,P,P) ----------------
template<int CIN>
__global__ void deform_k(const float* __restrict__ xp, const float* __restrict__ off,
                         const float* __restrict__ w, float* __restrict__ out){
  // block 256 = 64 pixels (8x8) x 4 osplits of 16 outputs; grid: (256 tiles, B)
  const int CCH = 16;
  __shared__ float wl[CCH*9*64];
  int tid = threadIdx.x;
  int px = tid & 7, py = (tid >> 3) & 7, osp = tid >> 6;
  int b = blockIdx.y;
  int tile = blockIdx.x;
  int wx = (tile & 15)*8 + px;
  int hy = (tile >> 4)*8 + py;
  float acc[16];
  #pragma unroll
  for (int i = 0; i < 16; i++) acc[i] = 0.f;
  const float* offb = off + (size_t)b*18*NP + hy*P + wx;
  const float* xb = xp + (size_t)b*CIN*NP;
  for (int c0 = 0; c0 < CIN; c0 += CCH){
    __syncthreads();
    for (int e = tid; e < CCH*9*64; e += 256){
      int o = e & 63; int r = e >> 6; int n = r % 9; int cl = r / 9;
      wl[e] = w[(o*CIN + c0 + cl)*9 + n];
    }
    __syncthreads();
    #pragma unroll
    for (int n = 0; n < 9; n++){
      float dy = offb[n*NP], dx = offb[(9+n)*NP];
      float ys = (float)hy + (float)(n/3 - 1) + dy;
      float xs = (float)wx + (float)(n%3 - 1) + dx;
      float y0f = floorf(ys), x0f = floorf(xs);
      float wy1 = ys - y0f, wx1 = xs - x0f;
      float wy0 = 1.f - wy1, wx0 = 1.f - wx1;
      int y0 = (int)y0f, x0 = (int)x0f;
      int y1i = y0 + 1, x1i = x0 + 1;
      bool v0y = ((unsigned)y0 < P), v1y = ((unsigned)y1i < P);
      bool v0x = ((unsigned)x0 < P), v1x = ((unsigned)x1i < P);
      float w00 = (v0y && v0x) ? wy0*wx0 : 0.f;
      float w01 = (v0y && v1x) ? wy0*wx1 : 0.f;
      float w10 = (v1y && v0x) ? wy1*wx0 : 0.f;
      float w11 = (v1y && v1x) ? wy1*wx1 : 0.f;
      int yc0 = min(max(y0,0),P-1)*P, yc1 = min(max(y1i,0),P-1)*P;
      int xc0 = min(max(x0,0),P-1),   xc1 = min(max(x1i,0),P-1);
      int i00 = yc0+xc0, i01 = yc0+xc1, i10 = yc1+xc0, i11 = yc1+xc1;
      const float* xc = xb + c0*NP;
      for (int cl = 0; cl < CCH; cl++){
        float s = w00*xc[i00] + w01*xc[i01] + w10*xc[i10] + w11*xc[i11];
        xc += NP;
        const float* wrow = &wl[(cl*9+n)*64 + osp*16];
        #pragma unroll
        for (int ob = 0; ob < 16; ob += 4){
          float4 w4 = *(const float4*)(wrow + ob);
          acc[ob]   = fmaf(s, w4.x, acc[ob]);
          acc[ob+1] = fmaf(s, w4.y, acc[ob+1]);
          acc[ob+2] = fmaf(s, w4.z, acc[ob+2]);
          acc[ob+3] = fmaf(s, w4.w, acc[ob+3]);
        }
      }
    }
  }
  float* ob = out + ((size_t)b*64 + osp*16)*NP + hy*P + wx;
  #pragma unroll
  for (int i = 0; i < 16; i++) ob[i*NP] = acc[i];
}

// ---------------- batchnorm stats: per channel scale/shift ----------------
__global__ void bnstats_k(const float* __restrict__ y, const float* __restrict__ g,
                          const float* __restrict__ be, float* __restrict__ stats){
  int ch = blockIdx.x; // 64 channels
  float s = 0.f, sq = 0.f;
  for (int i = threadIdx.x; i < BATCH*NP; i += blockDim.x){
    int bb = i >> 14; int pix = i & (NP-1);
    float v = y[((size_t)bb*64 + ch)*NP + pix];
    s += v; sq += v*v;
  }
  __shared__ float ss[2][8];
  for (int o = 32; o > 0; o >>= 1){
    s  += __shfl_down(s,  o, 64);
    sq += __shfl_down(sq, o, 64);
  }
  int wid = threadIdx.x >> 6, lane = threadIdx.x & 63;
  if (lane == 0){ ss[0][wid] = s; ss[1][wid] = sq; }
  __syncthreads();
  if (threadIdx.x == 0){
    float S = 0.f, SQ = 0.f;
    for (int i2 = 0; i2 < (int)blockDim.x/64; i2++){ S += ss[0][i2]; SQ += ss[1][i2]; }
    const float inv = 1.f/(float)(BATCH*NP);
    float mean = S * inv;
    float var = SQ * inv - mean*mean;
    float rstd = rsqrtf(var + 1e-5f);
    float scale = rstd * g[ch];
    stats[ch]      = scale;
    stats[64 + ch] = be[ch] - mean*scale;
  }
}

// ---------------- BN apply + relu, in place ----------------
__global__ void bnapply_k(float* __restrict__ y, const float* __restrict__ stats){
  int idx = blockIdx.x*256 + threadIdx.x;
  if (idx >= BATCH*64*NP) return;
  int ch = (idx >> 14) & 63;
  float v = y[idx]*stats[ch] + stats[64+ch];
  y[idx] = fmaxf(v, 0.f);
}

// ---------------- gates conv (128->256) fused with ConvLSTM pointwise ----------------
__global__ void gates_k(const float* __restrict__ x2, const float* __restrict__ h0,
                        const float* __restrict__ c0, const float* __restrict__ wg,
                        const float* __restrict__ bg, float* __restrict__ outh,
                        float* __restrict__ outc){
  // grid: (64 tiles of 16x16, co=64, b); block 256
  __shared__ float wl[4][128*9];
  int co = blockIdx.y, b = blockIdx.z;
  for (int e = threadIdx.x; e < 4*128*9; e += 256){
    int q = e / 1152, r = e % 1152;
    wl[q][r] = wg[(size_t)(q*64 + co)*1152 + r];
  }
  __syncthreads();
  int tile = blockIdx.x;
  int wx = (tile & 7)*16 + (threadIdx.x & 15);
  int hy = (tile >> 3)*16 + (threadIdx.x >> 4);
  float ai = bg[co], af = bg[64+co], ao = bg[128+co], ag = bg[192+co];
  for (int cin = 0; cin < 128; cin++){
    const float* inc = (cin < 64) ? (x2 + ((size_t)b*64 + cin)*NP)
                                  : (h0 + ((size_t)b*64 + (cin-64))*NP);
    #pragma unroll
    for (int ky = 0; ky < 3; ky++){
      int yy = hy + ky - 1;
      bool yok = ((unsigned)yy < P);
      #pragma unroll
      for (int kx = 0; kx < 3; kx++){
        int xx = wx + kx - 1;
        float v = (yok && (unsigned)xx < P) ? inc[yy*P+xx] : 0.f;
        int k = cin*9 + ky*3 + kx;
        ai = fmaf(v, wl[0][k], ai);
        af = fmaf(v, wl[1][k], af);
        ao = fmaf(v, wl[2][k], ao);
        ag = fmaf(v, wl[3][k], ag);
      }
    }
  }
  int pidx = ((b*64 + co)*NP) + hy*P + wx;
  float c0v = c0[pidx];
  float cv = sigmoidf_(af)*c0v + sigmoidf_(ai)*tanhf(ag);
  float hv = sigmoidf_(ao)*tanhf(cv);
  outh[pidx] = hv;
  outc[pidx] = cv;
}

extern "C" void kernel_launch(void* const* d_in, const int* in_sizes, int n_in,
                              void* d_out, int out_size, void* d_ws, size_t ws_size,
                              hipStream_t stream) {
  const float* x      = (const float*)d_in[0];
  const float* h0     = (const float*)d_in[1];
  const float* c0     = (const float*)d_in[2];
  const float* w_off1 = (const float*)d_in[3];
  const float* b_off1 = (const float*)d_in[4];
  const float* w1     = (const float*)d_in[5];
  const float* g1     = (const float*)d_in[6];
  const float* be1    = (const float*)d_in[7];
  const float* w_off2 = (const float*)d_in[8];
  const float* b_off2 = (const float*)d_in[9];
  const float* w2     = (const float*)d_in[10];
  const float* g2     = (const float*)d_in[11];
  const float* be2    = (const float*)d_in[12];
  const float* wg     = (const float*)d_in[13];
  const float* bg     = (const float*)d_in[14];

  float* ws    = (float*)d_ws;
  float* xp    = ws;                    // B*32*NP = 2097152
  float* off   = xp + 2097152;          // B*18*NP = 1179648
  float* y1    = off + 1179648;         // B*64*NP = 4194304
  float* y2    = y1 + 4194304;          // B*64*NP = 4194304
  float* stats = y2 + 4194304;          // 128

  maxpool_k<<<dim3((BATCH*32*NP + 255)/256), dim3(256), 0, stream>>>(x, xp);

  offconv_k<32><<<dim3(64, BATCH), dim3(256), 0, stream>>>(xp, w_off1, b_off1, off);
  deform_k<32><<<dim3(256, BATCH), dim3(256), 0, stream>>>(xp, off, w1, y1);
  bnstats_k<<<dim3(64), dim3(512), 0, stream>>>(y1, g1, be1, stats);
  bnapply_k<<<dim3((BATCH*64*NP + 255)/256), dim3(256), 0, stream>>>(y1, stats);

  offconv_k<64><<<dim3(64, BATCH), dim3(256), 0, stream>>>(y1, w_off2, b_off2, off);
  deform_k<64><<<dim3(256, BATCH), dim3(256), 0, stream>>>(y1, off, w2, y2);
  bnstats_k<<<dim3(64), dim3(512), 0, stream>>>(y2, g2, be2, stats);
  bnapply_k<<<dim3((BATCH*64*NP + 255)/256), dim3(256), 0, stream>>>(y2, stats);

  float* outh = (float*)d_out;
  float* outc = outh + (size_t)BATCH*64*NP;
  gates_k<<<dim3(64, 64, BATCH), dim3(256), 0, stream>>>(y2, h0, c0, wg, bg, outh, outc);
}

// Round 2
// 1731.017 us; speedup vs baseline: 1.5097x; 1.5097x over previous
//
#include <hip/hip_runtime.h>
#include <math.h>

#define P 128
#define NP (P*P)
#define BATCH 4

typedef __attribute__((ext_vector_type(8))) short bf16x8;
typedef __attribute__((ext_vector_type(4))) float f32x4;

__device__ __forceinline__ float sigmoidf_(float x){ return 1.f/(1.f+__expf(-x)); }
__device__ __forceinline__ short f2bf(float f){
  unsigned u = __builtin_bit_cast(unsigned, f);
  u = (u + 0x7FFFu + ((u>>16)&1u)) >> 16;
  return (short)u;
}

// ---------------- maxpool 2x2 stride 2: (B,32,256,256) -> (B,32,128,128) ----------------
__global__ void maxpool_k(const float* __restrict__ x, float* __restrict__ xp){
  int idx = blockIdx.x*256 + threadIdx.x;
  const int total = BATCH*32*NP;
  if (idx >= total) return;
  int wp = idx & (P-1); int t = idx >> 7; int hp = t & (P-1); int bc = t >> 7;
  const float* src = x + (((size_t)bc*256) + hp*2)*256 + wp*2;
  float a = src[0], b = src[1], c = src[256], d = src[257];
  xp[idx] = fmaxf(fmaxf(a,b), fmaxf(c,d));
}

// ---------------- direct 3x3 conv, Cin -> 18 offset channels ----------------
template<int CIN>
__global__ void offconv_k(const float* __restrict__ in, const float* __restrict__ w,
                          const float* __restrict__ bias, float* __restrict__ out){
  __shared__ float wl[18*CIN*9];
  for (int e = threadIdx.x; e < 18*CIN*9; e += 256) wl[e] = w[e];
  __syncthreads();
  int b = blockIdx.y;
  int tile = blockIdx.x;
  int wx = (tile & 7)*16 + (threadIdx.x & 15);
  int hy = (tile >> 3)*16 + (threadIdx.x >> 4);
  float acc[18];
  #pragma unroll
  for (int o = 0; o < 18; o++) acc[o] = bias[o];
  const float* inb = in + (size_t)b*CIN*NP;
  for (int c = 0; c < CIN; c++){
    const float* inc = inb + c*NP;
    #pragma unroll
    for (int ky = 0; ky < 3; ky++){
      int yy = hy + ky - 1;
      bool yok = ((unsigned)yy < P);
      #pragma unroll
      for (int kx = 0; kx < 3; kx++){
        int xx = wx + kx - 1;
        float v = (yok && (unsigned)xx < P) ? inc[yy*P+xx] : 0.f;
        const float* wp_ = &wl[c*9 + ky*3 + kx];
        #pragma unroll
        for (int o = 0; o < 18; o++) acc[o] = fmaf(v, wp_[o*CIN*9], acc[o]);
      }
    }
  }
  float* ob = out + (size_t)b*18*NP + hy*P + wx;
  #pragma unroll
  for (int o = 0; o < 18; o++) ob[o*NP] = acc[o];
}

// ---------------- deformable sample + einsum: (B,CIN,P,P)+(B,18,P,P) -> (B,64,P,P) ----------------
template<int CIN>
__global__ void deform_k(const float* __restrict__ xp, const float* __restrict__ off,
                         const float* __restrict__ w, float* __restrict__ out){
  const int CCH = 16;
  __shared__ float wl[CCH*9*64];
  int tid = threadIdx.x;
  int px = tid & 7, py = (tid >> 3) & 7, osp = tid >> 6;
  int b = blockIdx.y;
  int tile = blockIdx.x;
  int wx = (tile & 15)*8 + px;
  int hy = (tile >> 4)*8 + py;
  float acc[16];
  #pragma unroll
  for (int i = 0; i < 16; i++) acc[i] = 0.f;
  const float* offb = off + (size_t)b*18*NP + hy*P + wx;
  const float* xb = xp + (size_t)b*CIN*NP;
  for (int c0 = 0; c0 < CIN; c0 += CCH){
    __syncthreads();
    for (int e = tid; e < CCH*9*64; e += 256){
      int o = e & 63; int r = e >> 6; int n = r % 9; int cl = r / 9;
      wl[e] = w[(o*CIN + c0 + cl)*9 + n];
    }
    __syncthreads();
    #pragma unroll
    for (int n = 0; n < 9; n++){
      float dy = offb[n*NP], dx = offb[(9+n)*NP];
      float ys = (float)hy + (float)(n/3 - 1) + dy;
      float xs = (float)wx + (float)(n%3 - 1) + dx;
      float y0f = floorf(ys), x0f = floorf(xs);
      float wy1 = ys - y0f, wx1 = xs - x0f;
      float wy0 = 1.f - wy1, wx0 = 1.f - wx1;
      int y0 = (int)y0f, x0 = (int)x0f;
      int y1i = y0 + 1, x1i = x0 + 1;
      bool v0y = ((unsigned)y0 < P), v1y = ((unsigned)y1i < P);
      bool v0x = ((unsigned)x0 < P), v1x = ((unsigned)x1i < P);
      float w00 = (v0y && v0x) ? wy0*wx0 : 0.f;
      float w01 = (v0y && v1x) ? wy0*wx1 : 0.f;
      float w10 = (v1y && v0x) ? wy1*wx0 : 0.f;
      float w11 = (v1y && v1x) ? wy1*wx1 : 0.f;
      int yc0 = min(max(y0,0),P-1)*P, yc1 = min(max(y1i,0),P-1)*P;
      int xc0 = min(max(x0,0),P-1),   xc1 = min(max(x1i,0),P-1);
      int i00 = yc0+xc0, i01 = yc0+xc1, i10 = yc1+xc0, i11 = yc1+xc1;
      const float* xc = xb + c0*NP;
      for (int cl = 0; cl < CCH; cl++){
        float s = w00*xc[i00] + w01*xc[i01] + w10*xc[i10] + w11*xc[i11];
        xc += NP;
        const float* wrow = &wl[(cl*9+n)*64 + osp*16];
        #pragma unroll
        for (int ob = 0; ob < 16; ob += 4){
          float4 w4 = *(const float4*)(wrow + ob);
          acc[ob]   = fmaf(s, w4.x, acc[ob]);
          acc[ob+1] = fmaf(s, w4.y, acc[ob+1]);
          acc[ob+2] = fmaf(s, w4.z, acc[ob+2]);
          acc[ob+3] = fmaf(s, w4.w, acc[ob+3]);
        }
      }
    }
  }
  float* ob = out + ((size_t)b*64 + osp*16)*NP + hy*P + wx;
  #pragma unroll
  for (int i = 0; i < 16; i++) ob[i*NP] = acc[i];
}

// ---------------- batchnorm stats ----------------
__global__ void bnstats_k(const float* __restrict__ y, const float* __restrict__ g,
                          const float* __restrict__ be, float* __restrict__ stats){
  int ch = blockIdx.x;
  float s = 0.f, sq = 0.f;
  for (int i = threadIdx.x; i < BATCH*NP; i += blockDim.x){
    int bb = i >> 14; int pix = i & (NP-1);
    float v = y[((size_t)bb*64 + ch)*NP + pix];
    s += v; sq += v*v;
  }
  __shared__ float ss[2][8];
  for (int o = 32; o > 0; o >>= 1){
    s  += __shfl_down(s,  o, 64);
    sq += __shfl_down(sq, o, 64);
  }
  int wid = threadIdx.x >> 6, lane = threadIdx.x & 63;
  if (lane == 0){ ss[0][wid] = s; ss[1][wid] = sq; }
  __syncthreads();
  if (threadIdx.x == 0){
    float S = 0.f, SQ = 0.f;
    for (int i2 = 0; i2 < (int)blockDim.x/64; i2++){ S += ss[0][i2]; SQ += ss[1][i2]; }
    const float inv = 1.f/(float)(BATCH*NP);
    float mean = S * inv;
    float var = SQ * inv - mean*mean;
    float rstd = rsqrtf(var + 1e-5f);
    float scale = rstd * g[ch];
    stats[ch]      = scale;
    stats[64 + ch] = be[ch] - mean*scale;
  }
}

// ---------------- BN apply + relu ----------------
__global__ void bnapply_k(float* __restrict__ y, const float* __restrict__ stats){
  int idx = blockIdx.x*256 + threadIdx.x;
  if (idx >= BATCH*64*NP) return;
  int ch = (idx >> 14) & 63;
  float v = y[idx]*stats[ch] + stats[64+ch];
  y[idx] = fmaxf(v, 0.f);
}

// ---------------- weight prep: wg (256,128,3,3) -> wT[tap][ch*4+gate][cin] bf16 ----------------
__global__ void wprep_k(const float* __restrict__ wg, short* __restrict__ wT){
  int idx = blockIdx.x*256 + threadIdx.x;
  if (idx >= 9*256*128) return;
  int cin = idx & 127; int t = idx >> 7; int gidx = t & 255; int tap = t >> 8;
  int ch = gidx >> 2, gate = gidx & 3;
  wT[idx] = f2bf(wg[((size_t)(gate*64 + ch)*128 + cin)*9 + tap]);
}

// ---------------- gates conv (128->256) as implicit-GEMM MFMA + fused LSTM ----------------
// grid: (128 pixel-tiles of 16x8, 4 channel-tiles, B); block 256 = 4 waves.
// M = 64 (16 channels x 4 gates interleaved), N = 128 pixels, K = 9 taps x 128 cin.
__global__ __launch_bounds__(256) void gates_mfma_k(
    const float* __restrict__ x2, const float* __restrict__ h0,
    const float* __restrict__ c0, const short* __restrict__ wT,
    const float* __restrict__ bg, float* __restrict__ outh,
    float* __restrict__ outc){
  __shared__ short xs[180*128];   // halo tile (10x18 pixels) x 128 cin, XOR-swizzled, 46080 B
  int tid = threadIdx.x;
  int tile = blockIdx.x, ct = blockIdx.y, b = blockIdx.z;
  int tx0 = (tile & 7)*16, ty0 = (tile >> 3)*8;

  const float* xb = x2 + (size_t)b*64*NP;
  const float* hb = h0 + (size_t)b*64*NP;
  // stage: e = (channel-group cg of 8 cin) x (halo pixel p)
  for (int e = tid; e < 2880; e += 256){
    int p = e % 180; int cg = e / 180;
    int hr = p/18, wc = p%18;
    int gy = ty0 + hr - 1, gx = tx0 + wc - 1;
    bool ok = ((unsigned)gy < P) && ((unsigned)gx < P);
    const float* src = ((cg < 8) ? (xb + (size_t)(cg*8)*NP) : (hb + (size_t)(cg*8-64)*NP))
                       + gy*P + gx;
    union { short s[8]; bf16x8 v; } u;
    #pragma unroll
    for (int j = 0; j < 8; j++) u.s[j] = ok ? f2bf(src[(size_t)j*NP]) : (short)0;
    int boff = p*256 + ((cg*16) ^ ((p&7)<<4));
    *(bf16x8*)((char*)xs + boff) = u.v;
  }
  __syncthreads();

  int lane = tid & 63, wid = tid >> 6;
  int kg = lane >> 4, ln = lane & 15;
  f32x4 acc[4][2];
  #pragma unroll
  for (int mf = 0; mf < 4; mf++)
    #pragma unroll
    for (int r = 0; r < 2; r++) acc[mf][r] = (f32x4){0.f,0.f,0.f,0.f};

  // A-frag base: gidx = ct*64 + mf*16 + ln ; cin = cb*32 + kg*8 + j
  const short* wb0 = wT + (size_t)(ct*64 + ln)*128 + kg*8;
  #pragma unroll
  for (int tap = 0; tap < 9; tap++){
    const int ky = tap/3, kx = tap%3;
    const short* wt = wb0 + (size_t)tap*(256*128);
    #pragma unroll
    for (int cb = 0; cb < 4; cb++){
      bf16x8 af[4];
      #pragma unroll
      for (int mf = 0; mf < 4; mf++)
        af[mf] = *(const bf16x8*)(wt + mf*16*128 + cb*32);
      #pragma unroll
      for (int r = 0; r < 2; r++){
        int hrow = wid*2 + r + ky;
        int p = hrow*18 + ln + kx;
        int boff = p*256 + (((cb*64) + kg*16) ^ ((p&7)<<4));
        bf16x8 bfv = *(const bf16x8*)((const char*)xs + boff);
        #pragma unroll
        for (int mf = 0; mf < 4; mf++)
          acc[mf][r] = __builtin_amdgcn_mfma_f32_16x16x32_bf16(af[mf], bfv, acc[mf][r], 0, 0, 0);
      }
    }
  }

  // epilogue: acc[mf][r] regs 0..3 = (i,f,o,g) for channel ct*16+mf*4+kg, pixel (ty0+wid*2+r, tx0+ln)
  #pragma unroll
  for (int mf = 0; mf < 4; mf++){
    int ch = ct*16 + mf*4 + kg;
    float bi = bg[ch], bff = bg[64+ch], bo = bg[128+ch], bgv = bg[192+ch];
    #pragma unroll
    for (int r = 0; r < 2; r++){
      int py = ty0 + wid*2 + r, px = tx0 + ln;
      size_t pidx = ((size_t)(b*64 + ch))*NP + py*P + px;
      f32x4 a = acc[mf][r];
      float cv = sigmoidf_(a[1]+bff)*c0[pidx] + sigmoidf_(a[0]+bi)*tanhf(a[3]+bgv);
      float hv = sigmoidf_(a[2]+bo)*tanhf(cv);
      outh[pidx] = hv;
      outc[pidx] = cv;
    }
  }
}

extern "C" void kernel_launch(void* const* d_in, const int* in_sizes, int n_in,
                              void* d_out, int out_size, void* d_ws, size_t ws_size,
                              hipStream_t stream) {
  const float* x      = (const float*)d_in[0];
  const float* h0     = (const float*)d_in[1];
  const float* c0     = (const float*)d_in[2];
  const float* w_off1 = (const float*)d_in[3];
  const float* b_off1 = (const float*)d_in[4];
  const float* w1     = (const float*)d_in[5];
  const float* g1     = (const float*)d_in[6];
  const float* be1    = (const float*)d_in[7];
  const float* w_off2 = (const float*)d_in[8];
  const float* b_off2 = (const float*)d_in[9];
  const float* w2     = (const float*)d_in[10];
  const float* g2     = (const float*)d_in[11];
  const float* be2    = (const float*)d_in[12];
  const float* wg     = (const float*)d_in[13];
  const float* bg     = (const float*)d_in[14];

  float* ws    = (float*)d_ws;
  float* xp    = ws;                    // B*32*NP = 2097152
  float* off   = xp + 2097152;          // B*18*NP = 1179648
  float* y1    = off + 1179648;         // B*64*NP = 4194304
  float* y2    = y1 + 4194304;          // B*64*NP = 4194304
  float* stats = y2 + 4194304;          // 128
  short* wT    = (short*)(stats + 128); // 9*256*128 bf16 = 294912

  maxpool_k<<<dim3((BATCH*32*NP + 255)/256), dim3(256), 0, stream>>>(x, xp);
  wprep_k<<<dim3((9*256*128 + 255)/256), dim3(256), 0, stream>>>(wg, wT);

  offconv_k<32><<<dim3(64, BATCH), dim3(256), 0, stream>>>(xp, w_off1, b_off1, off);
  deform_k<32><<<dim3(256, BATCH), dim3(256), 0, stream>>>(xp, off, w1, y1);
  bnstats_k<<<dim3(64), dim3(512), 0, stream>>>(y1, g1, be1, stats);
  bnapply_k<<<dim3((BATCH*64*NP + 255)/256), dim3(256), 0, stream>>>(y1, stats);

  offconv_k<64><<<dim3(64, BATCH), dim3(256), 0, stream>>>(y1, w_off2, b_off2, off);
  deform_k<64><<<dim3(256, BATCH), dim3(256), 0, stream>>>(y1, off, w2, y2);
  bnstats_k<<<dim3(64), dim3(512), 0, stream>>>(y2, g2, be2, stats);
  bnapply_k<<<dim3((BATCH*64*NP + 255)/256), dim3(256), 0, stream>>>(y2, stats);

  float* outh = (float*)d_out;
  float* outc = outh + (size_t)BATCH*64*NP;
  gates_mfma_k<<<dim3(128, 4, BATCH), dim3(256), 0, stream>>>(y2, h0, c0, wT, bg, outh, outc);
}

// Round 3
// 505.242 us; speedup vs baseline: 5.1724x; 3.4261x over previous
//
#include <hip/hip_runtime.h>
#include <math.h>

#define P 128
#define NP (P*P)
#define BATCH 4

typedef __attribute__((ext_vector_type(8))) short bf16x8;
typedef __attribute__((ext_vector_type(4))) float f32x4;

__device__ __forceinline__ float sigmoidf_(float x){ return 1.f/(1.f+__expf(-x)); }
__device__ __forceinline__ short f2bf(float f){
  unsigned u = __builtin_bit_cast(unsigned, f);
  u = (u + 0x7FFFu + ((u>>16)&1u)) >> 16;
  return (short)u;
}

// ---------------- maxpool 2x2 stride 2: (B,32,256,256) planar -> (B,P,P,32) channels-last ----------------
__global__ void maxpool_cl_k(const float* __restrict__ x, float* __restrict__ xp){
  int idx = blockIdx.x*256 + threadIdx.x;   // b*NP + pix
  if (idx >= BATCH*NP) return;
  int wp = idx & (P-1); int t = idx >> 7; int hp = t & (P-1); int b = t >> 7;
  const float* src = x + ((size_t)b*32*65536) + (size_t)(hp*2)*256 + wp*2;
  float m[32];
  #pragma unroll
  for (int c = 0; c < 32; c++){
    const float* s = src + (size_t)c*65536;
    m[c] = fmaxf(fmaxf(s[0], s[1]), fmaxf(s[256], s[257]));
  }
  float* dst = xp + (size_t)idx*32;
  #pragma unroll
  for (int q = 0; q < 8; q++) *(float4*)(dst + q*4) = *(float4*)(m + q*4);
}

// ---------------- fused weight prep (all bf16 transposes) ----------------
// wT   [tap][ch*4+gate][128]            294912
// wd1T [tap][o64][32]                    18432
// wd2T [tap][o64][64]                    36864
// woT1 [tap][o32(18)][32]                 9216
// woT2 [tap][o32(18)][64]                18432
__global__ void wprep_all_k(const float* __restrict__ wg, const float* __restrict__ w1,
                            const float* __restrict__ w2, const float* __restrict__ wo1,
                            const float* __restrict__ wo2,
                            short* __restrict__ wT, short* __restrict__ wd1T,
                            short* __restrict__ wd2T, short* __restrict__ woT1,
                            short* __restrict__ woT2){
  int idx = blockIdx.x*256 + threadIdx.x;
  if (idx < 294912){
    int cin = idx & 127; int t = idx >> 7; int gidx = t & 255; int tap = t >> 8;
    int ch = gidx >> 2, gate = gidx & 3;
    wT[idx] = f2bf(wg[((size_t)(gate*64 + ch)*128 + cin)*9 + tap]);
    return;
  }
  idx -= 294912;
  if (idx < 18432){
    int c = idx & 31; int t = idx >> 5; int o = t & 63; int tap = t >> 6;
    wd1T[idx] = f2bf(w1[(size_t)(o*32 + c)*9 + tap]);
    return;
  }
  idx -= 18432;
  if (idx < 36864){
    int c = idx & 63; int t = idx >> 6; int o = t & 63; int tap = t >> 6;
    wd2T[idx] = f2bf(w2[(size_t)(o*64 + c)*9 + tap]);
    return;
  }
  idx -= 36864;
  if (idx < 9216){
    int c = idx & 31; int t = idx >> 5; int o = t & 31; int tap = t >> 5;
    woT1[idx] = (o < 18) ? f2bf(wo1[(size_t)(o*32 + c)*9 + tap]) : (short)0;
    return;
  }
  idx -= 9216;
  if (idx < 18432){
    int c = idx & 63; int t = idx >> 6; int o = t & 31; int tap = t >> 5;
    woT2[idx] = (o < 18) ? f2bf(wo2[(size_t)(o*64 + c)*9 + tap]) : (short)0;
  }
}

// ---------------- offset conv as MFMA: channels-last in, planar 18-ch out ----------------
// M=32 (18 real), K=CIN*9, N=128 px (16x8). grid (128, B), block 256.
template<int CIN>
__global__ __launch_bounds__(256) void offconv_mfma_k(
    const float* __restrict__ incl, const short* __restrict__ woT,
    const float* __restrict__ bias, float* __restrict__ off_out){
  const int ROWB = CIN*2;
  const int PMASK = CIN/8 - 1;
  __shared__ short xs[180*CIN];
  int tid = threadIdx.x;
  int tile = blockIdx.x, b = blockIdx.y;
  int tx0 = (tile & 7)*16, ty0 = (tile >> 3)*8;
  const float* inb = incl + (size_t)b*NP*CIN;
  for (int e = tid; e < 180*(CIN/8); e += 256){
    int p = e % 180, cg = e / 180;
    int hr = p/18, wc = p%18;
    int gy = ty0 + hr - 1, gx = tx0 + wc - 1;
    bool ok = ((unsigned)gy < P) && ((unsigned)gx < P);
    union { short s[8]; bf16x8 v; } u;
    if (ok){
      const float* src = inb + ((size_t)gy*P + gx)*CIN + cg*8;
      float4 a = *(const float4*)src, bb = *(const float4*)(src+4);
      u.s[0]=f2bf(a.x); u.s[1]=f2bf(a.y); u.s[2]=f2bf(a.z); u.s[3]=f2bf(a.w);
      u.s[4]=f2bf(bb.x); u.s[5]=f2bf(bb.y); u.s[6]=f2bf(bb.z); u.s[7]=f2bf(bb.w);
    } else {
      #pragma unroll
      for (int j = 0; j < 8; j++) u.s[j] = 0;
    }
    int boff = p*ROWB + ((cg*16) ^ ((p & PMASK)<<4));
    *(bf16x8*)((char*)xs + boff) = u.v;
  }
  __syncthreads();
  int lane = tid & 63, wid = tid >> 6;
  int kg = lane >> 4, ln = lane & 15;
  f32x4 acc[2][2];
  #pragma unroll
  for (int mf = 0; mf < 2; mf++)
    #pragma unroll
    for (int r = 0; r < 2; r++) acc[mf][r] = (f32x4){0.f,0.f,0.f,0.f};
  #pragma unroll
  for (int tap = 0; tap < 9; tap++){
    const int ky = tap/3, kx = tap%3;
    #pragma unroll
    for (int cb = 0; cb < CIN/32; cb++){
      bf16x8 af[2];
      #pragma unroll
      for (int mf = 0; mf < 2; mf++)
        af[mf] = *(const bf16x8*)(woT + ((size_t)(tap*32 + mf*16 + ln)*CIN + cb*32 + kg*8));
      #pragma unroll
      for (int r = 0; r < 2; r++){
        int p = (wid*2 + r + ky)*18 + ln + kx;
        int boff = p*ROWB + ((cb*64 + kg*16) ^ ((p & PMASK)<<4));
        bf16x8 bfv = *(const bf16x8*)((const char*)xs + boff);
        #pragma unroll
        for (int mf = 0; mf < 2; mf++)
          acc[mf][r] = __builtin_amdgcn_mfma_f32_16x16x32_bf16(af[mf], bfv, acc[mf][r], 0, 0, 0);
      }
    }
  }
  #pragma unroll
  for (int mf = 0; mf < 2; mf++){
    #pragma unroll
    for (int r = 0; r < 2; r++){
      int py = ty0 + wid*2 + r, px = tx0 + ln;
      #pragma unroll
      for (int j = 0; j < 4; j++){
        int o = mf*16 + kg*4 + j;
        if (o < 18)
          off_out[((size_t)(b*18 + o))*NP + py*P + px] = acc[mf][r][j] + bias[o];
      }
    }
  }
}

// ---------------- deformable conv as MFMA: sample per tap into LDS, GEMM over K=CIN*9 ----------------
// out channels-last (B,P,P,64). grid (128, B), block 256.
template<int CIN>
__global__ __launch_bounds__(256) void deform_mfma_k(
    const float* __restrict__ incl, const float* __restrict__ off,
    const short* __restrict__ wdT, float* __restrict__ outcl){
  const int ROWB = CIN*2;
  const int PMASK = CIN/8 - 1;
  __shared__ short s_lds[128*CIN];
  int tid = threadIdx.x;
  int tile = blockIdx.x, b = blockIdx.y;
  int tx0 = (tile & 7)*16, ty0 = (tile >> 3)*8;
  int lane = tid & 63, wid = tid >> 6;
  int kg = lane >> 4, ln = lane & 15;
  // staging mapping
  int sp = tid & 127, shalf = tid >> 7;
  int spx = sp & 15, spy = sp >> 4;
  int gy = ty0 + spy, gx = tx0 + spx;
  const float* inb = incl + (size_t)b*NP*CIN;
  const float* offb = off + (size_t)b*18*NP + gy*P + gx;
  f32x4 acc[4][2];
  #pragma unroll
  for (int mf = 0; mf < 4; mf++)
    #pragma unroll
    for (int r = 0; r < 2; r++) acc[mf][r] = (f32x4){0.f,0.f,0.f,0.f};

  for (int tap = 0; tap < 9; tap++){
    // ---- sample this tap for all 128 px x CIN ch into LDS (bf16, swizzled)
    float dy = offb[(size_t)tap*NP], dx = offb[(size_t)(9+tap)*NP];
    float ys = (float)gy + (float)(tap/3 - 1) + dy;
    float xsm = (float)gx + (float)(tap%3 - 1) + dx;
    float y0f = floorf(ys), x0f = floorf(xsm);
    float wy1 = ys - y0f, wx1 = xsm - x0f;
    float wy0 = 1.f - wy1, wx0 = 1.f - wx1;
    int y0 = (int)y0f, x0 = (int)x0f;
    int y1i = y0 + 1, x1i = x0 + 1;
    bool v0y = ((unsigned)y0 < P), v1y = ((unsigned)y1i < P);
    bool v0x = ((unsigned)x0 < P), v1x = ((unsigned)x1i < P);
    float w00 = (v0y && v0x) ? wy0*wx0 : 0.f;
    float w01 = (v0y && v1x) ? wy0*wx1 : 0.f;
    float w10 = (v1y && v0x) ? wy1*wx0 : 0.f;
    float w11 = (v1y && v1x) ? wy1*wx1 : 0.f;
    int yc0 = min(max(y0,0),P-1), yc1 = min(max(y1i,0),P-1);
    int xc0 = min(max(x0,0),P-1), xc1 = min(max(x1i,0),P-1);
    const float* p00 = inb + ((size_t)yc0*P + xc0)*CIN;
    const float* p01 = inb + ((size_t)yc0*P + xc1)*CIN;
    const float* p10 = inb + ((size_t)yc1*P + xc0)*CIN;
    const float* p11 = inb + ((size_t)yc1*P + xc1)*CIN;
    __syncthreads();   // previous MFMA reads done before overwrite
    #pragma unroll
    for (int it = 0; it < CIN/16; it++){
      int c0 = shalf*(CIN/2) + it*8;
      float4 a0 = *(const float4*)(p00 + c0), a1 = *(const float4*)(p00 + c0 + 4);
      float4 b0 = *(const float4*)(p01 + c0), b1 = *(const float4*)(p01 + c0 + 4);
      float4 c0v = *(const float4*)(p10 + c0), c1v = *(const float4*)(p10 + c0 + 4);
      float4 d0 = *(const float4*)(p11 + c0), d1 = *(const float4*)(p11 + c0 + 4);
      union { short s[8]; bf16x8 v; } u;
      u.s[0] = f2bf(w00*a0.x + w01*b0.x + w10*c0v.x + w11*d0.x);
      u.s[1] = f2bf(w00*a0.y + w01*b0.y + w10*c0v.y + w11*d0.y);
      u.s[2] = f2bf(w00*a0.z + w01*b0.z + w10*c0v.z + w11*d0.z);
      u.s[3] = f2bf(w00*a0.w + w01*b0.w + w10*c0v.w + w11*d0.w);
      u.s[4] = f2bf(w00*a1.x + w01*b1.x + w10*c1v.x + w11*d1.x);
      u.s[5] = f2bf(w00*a1.y + w01*b1.y + w10*c1v.y + w11*d1.y);
      u.s[6] = f2bf(w00*a1.z + w01*b1.z + w10*c1v.z + w11*d1.z);
      u.s[7] = f2bf(w00*a1.w + w01*b1.w + w10*c1v.w + w11*d1.w);
      int boff = sp*ROWB + ((c0*2) ^ ((sp & PMASK)<<4));
      *(bf16x8*)((char*)s_lds + boff) = u.v;
    }
    __syncthreads();
    // ---- MFMA this tap
    #pragma unroll
    for (int cb = 0; cb < CIN/32; cb++){
      bf16x8 af[4];
      #pragma unroll
      for (int mf = 0; mf < 4; mf++)
        af[mf] = *(const bf16x8*)(wdT + ((size_t)(tap*64 + mf*16 + ln)*CIN + cb*32 + kg*8));
      #pragma unroll
      for (int r = 0; r < 2; r++){
        int p = (wid*2 + r)*16 + ln;
        int boff = p*ROWB + ((cb*64 + kg*16) ^ ((p & PMASK)<<4));
        bf16x8 bfv = *(const bf16x8*)((const char*)s_lds + boff);
        #pragma unroll
        for (int mf = 0; mf < 4; mf++)
          acc[mf][r] = __builtin_amdgcn_mfma_f32_16x16x32_bf16(af[mf], bfv, acc[mf][r], 0, 0, 0);
      }
    }
  }
  // epilogue: channels-last float4 stores
  #pragma unroll
  for (int mf = 0; mf < 4; mf++){
    #pragma unroll
    for (int r = 0; r < 2; r++){
      int py = ty0 + wid*2 + r, px = tx0 + ln;
      float* dst = outcl + ((size_t)b*NP + (size_t)py*P + px)*64 + mf*16 + kg*4;
      *(f32x4*)dst = acc[mf][r];
    }
  }
}

// ---------------- BN stats (channels-last): partial sums then finalize ----------------
__global__ void bnsum_k(const float* __restrict__ y, float* __restrict__ part){
  int lane = threadIdx.x & 63, wid = threadIdx.x >> 6;
  float s = 0.f, sq = 0.f;
  for (int pix = blockIdx.x*4 + wid; pix < BATCH*NP; pix += 256){
    float v = y[(size_t)pix*64 + lane];
    s += v; sq += v*v;
  }
  __shared__ float red[4][128];
  red[wid][lane] = s; red[wid][64+lane] = sq;
  __syncthreads();
  if (wid == 0){
    float S = red[0][lane]+red[1][lane]+red[2][lane]+red[3][lane];
    float Q = red[0][64+lane]+red[1][64+lane]+red[2][64+lane]+red[3][64+lane];
    part[blockIdx.x*128 + lane] = S;
    part[blockIdx.x*128 + 64 + lane] = Q;
  }
}

__global__ void bnfinal_k(const float* __restrict__ part, const float* __restrict__ g,
                          const float* __restrict__ be, float* __restrict__ stats){
  int ch = threadIdx.x;
  float S = 0.f, Q = 0.f;
  for (int i = 0; i < 64; i++){ S += part[i*128 + ch]; Q += part[i*128 + 64 + ch]; }
  const float inv = 1.f/(float)(BATCH*NP);
  float mean = S*inv;
  float var = Q*inv - mean*mean;
  float scale = rsqrtf(var + 1e-5f)*g[ch];
  stats[ch] = scale;
  stats[64+ch] = be[ch] - mean*scale;
}

__global__ void bnapply_cl_k(float* __restrict__ y, const float* __restrict__ stats){
  int idx = blockIdx.x*256 + threadIdx.x;  // over B*NP*16 float4s
  if (idx >= BATCH*NP*16) return;
  int ch4 = (idx & 15)*4;
  float4 v = ((float4*)y)[idx];
  v.x = fmaxf(v.x*stats[ch4+0] + stats[64+ch4+0], 0.f);
  v.y = fmaxf(v.y*stats[ch4+1] + stats[64+ch4+1], 0.f);
  v.z = fmaxf(v.z*stats[ch4+2] + stats[64+ch4+2], 0.f);
  v.w = fmaxf(v.w*stats[ch4+3] + stats[64+ch4+3], 0.f);
  ((float4*)y)[idx] = v;
}

// ---------------- gates conv (128->256) MFMA + fused LSTM (y2 channels-last, h0 planar) ----------------
__global__ __launch_bounds__(256) void gates_mfma_k(
    const float* __restrict__ y2cl, const float* __restrict__ h0,
    const float* __restrict__ c0, const short* __restrict__ wT,
    const float* __restrict__ bg, float* __restrict__ outh,
    float* __restrict__ outc){
  __shared__ short xs[180*128];
  int tid = threadIdx.x;
  int tile = blockIdx.x, ct = blockIdx.y, b = blockIdx.z;
  int tx0 = (tile & 7)*16, ty0 = (tile >> 3)*8;

  const float* yb = y2cl + (size_t)b*NP*64;
  const float* hb = h0 + (size_t)b*64*NP;
  for (int e = tid; e < 2880; e += 256){
    int p = e % 180; int cg = e / 180;
    int hr = p/18, wc = p%18;
    int gy = ty0 + hr - 1, gx = tx0 + wc - 1;
    bool ok = ((unsigned)gy < P) && ((unsigned)gx < P);
    union { short s[8]; bf16x8 v; } u;
    if (!ok){
      #pragma unroll
      for (int j = 0; j < 8; j++) u.s[j] = 0;
    } else if (cg < 8){
      const float* src = yb + ((size_t)gy*P + gx)*64 + cg*8;
      float4 a = *(const float4*)src, bb = *(const float4*)(src+4);
      u.s[0]=f2bf(a.x); u.s[1]=f2bf(a.y); u.s[2]=f2bf(a.z); u.s[3]=f2bf(a.w);
      u.s[4]=f2bf(bb.x); u.s[5]=f2bf(bb.y); u.s[6]=f2bf(bb.z); u.s[7]=f2bf(bb.w);
    } else {
      const float* src = hb + (size_t)(cg-8)*8*NP + (size_t)gy*P + gx;
      #pragma unroll
      for (int j = 0; j < 8; j++) u.s[j] = f2bf(src[(size_t)j*NP]);
    }
    int boff = p*256 + ((cg*16) ^ ((p&7)<<4));
    *(bf16x8*)((char*)xs + boff) = u.v;
  }
  __syncthreads();

  int lane = tid & 63, wid = tid >> 6;
  int kg = lane >> 4, ln = lane & 15;
  f32x4 acc[4][2];
  #pragma unroll
  for (int mf = 0; mf < 4; mf++)
    #pragma unroll
    for (int r = 0; r < 2; r++) acc[mf][r] = (f32x4){0.f,0.f,0.f,0.f};

  const short* wb0 = wT + (size_t)(ct*64 + ln)*128 + kg*8;
  #pragma unroll
  for (int tap = 0; tap < 9; tap++){
    const int ky = tap/3, kx = tap%3;
    const short* wt = wb0 + (size_t)tap*(256*128);
    #pragma unroll
    for (int cb = 0; cb < 4; cb++){
      bf16x8 af[4];
      #pragma unroll
      for (int mf = 0; mf < 4; mf++)
        af[mf] = *(const bf16x8*)(wt + mf*16*128 + cb*32);
      #pragma unroll
      for (int r = 0; r < 2; r++){
        int hrow = wid*2 + r + ky;
        int p = hrow*18 + ln + kx;
        int boff = p*256 + (((cb*64) + kg*16) ^ ((p&7)<<4));
        bf16x8 bfv = *(const bf16x8*)((const char*)xs + boff);
        #pragma unroll
        for (int mf = 0; mf < 4; mf++)
          acc[mf][r] = __builtin_amdgcn_mfma_f32_16x16x32_bf16(af[mf], bfv, acc[mf][r], 0, 0, 0);
      }
    }
  }

  #pragma unroll
  for (int mf = 0; mf < 4; mf++){
    int ch = ct*16 + mf*4 + kg;
    float bi = bg[ch], bff = bg[64+ch], bo = bg[128+ch], bgv = bg[192+ch];
    #pragma unroll
    for (int r = 0; r < 2; r++){
      int py = ty0 + wid*2 + r, px = tx0 + ln;
      size_t pidx = ((size_t)(b*64 + ch))*NP + (size_t)py*P + px;
      f32x4 a = acc[mf][r];
      float cv = sigmoidf_(a[1]+bff)*c0[pidx] + sigmoidf_(a[0]+bi)*tanhf(a[3]+bgv);
      float hv = sigmoidf_(a[2]+bo)*tanhf(cv);
      outh[pidx] = hv;
      outc[pidx] = cv;
    }
  }
}

extern "C" void kernel_launch(void* const* d_in, const int* in_sizes, int n_in,
                              void* d_out, int out_size, void* d_ws, size_t ws_size,
                              hipStream_t stream) {
  const float* x      = (const float*)d_in[0];
  const float* h0     = (const float*)d_in[1];
  const float* c0     = (const float*)d_in[2];
  const float* w_off1 = (const float*)d_in[3];
  const float* b_off1 = (const float*)d_in[4];
  const float* w1     = (const float*)d_in[5];
  const float* g1     = (const float*)d_in[6];
  const float* be1    = (const float*)d_in[7];
  const float* w_off2 = (const float*)d_in[8];
  const float* b_off2 = (const float*)d_in[9];
  const float* w2     = (const float*)d_in[10];
  const float* g2     = (const float*)d_in[11];
  const float* be2    = (const float*)d_in[12];
  const float* wg     = (const float*)d_in[13];
  const float* bg     = (const float*)d_in[14];

  float* ws    = (float*)d_ws;
  float* xpcl  = ws;                     // B*NP*32 = 2097152
  float* off   = xpcl + 2097152;         // B*18*NP = 1179648
  float* y1    = off + 1179648;          // B*NP*64 = 4194304 (channels-last)
  float* y2    = y1 + 4194304;           // 4194304 (channels-last)
  float* part  = y2 + 4194304;           // 8192
  float* stats = part + 8192;            // 128
  short* wT    = (short*)(stats + 128);  // 294912
  short* wd1T  = wT + 294912;            // 18432
  short* wd2T  = wd1T + 18432;           // 36864
  short* woT1  = wd2T + 36864;           // 9216
  short* woT2  = woT1 + 9216;            // 18432

  maxpool_cl_k<<<dim3((BATCH*NP + 255)/256), dim3(256), 0, stream>>>(x, xpcl);
  wprep_all_k<<<dim3((377856 + 255)/256), dim3(256), 0, stream>>>(
      wg, w1, w2, w_off1, w_off2, wT, wd1T, wd2T, woT1, woT2);

  offconv_mfma_k<32><<<dim3(128, BATCH), dim3(256), 0, stream>>>(xpcl, woT1, b_off1, off);
  deform_mfma_k<32><<<dim3(128, BATCH), dim3(256), 0, stream>>>(xpcl, off, wd1T, y1);
  bnsum_k<<<dim3(64), dim3(256), 0, stream>>>(y1, part);
  bnfinal_k<<<dim3(1), dim3(64), 0, stream>>>(part, g1, be1, stats);
  bnapply_cl_k<<<dim3((BATCH*NP*16 + 255)/256), dim3(256), 0, stream>>>(y1, stats);

  offconv_mfma_k<64><<<dim3(128, BATCH), dim3(256), 0, stream>>>(y1, woT2, b_off2, off);
  deform_mfma_k<64><<<dim3(128, BATCH), dim3(256), 0, stream>>>(y1, off, wd2T, y2);
  bnsum_k<<<dim3(64), dim3(256), 0, stream>>>(y2, part);
  bnfinal_k<<<dim3(1), dim3(64), 0, stream>>>(part, g2, be2, stats);
  bnapply_cl_k<<<dim3((BATCH*NP*16 + 255)/256), dim3(256), 0, stream>>>(y2, stats);

  float* outh = (float*)d_out;
  float* outc = outh + (size_t)BATCH*64*NP;
  gates_mfma_k<<<dim3(128, 4, BATCH), dim3(256), 0, stream>>>(y2, h0, c0, wT, bg, outh, outc);
}

// Round 4
// 379.536 us; speedup vs baseline: 6.8855x; 1.3312x over previous
//
#include <hip/hip_runtime.h>
#include <math.h>

#define P 128
#define NP (P*P)
#define BATCH 4

typedef __attribute__((ext_vector_type(8))) short bf16x8;
typedef __attribute__((ext_vector_type(4))) float f32x4;

__device__ __forceinline__ float sigmoidf_(float x){ return 1.f/(1.f+__expf(-x)); }
__device__ __forceinline__ short f2bf(float f){
  unsigned u = __builtin_bit_cast(unsigned, f);
  u = (u + 0x7FFFu + ((u>>16)&1u)) >> 16;
  return (short)u;
}

// ---------------- maxpool 2x2 stride 2: (B,32,256,256) planar -> (B,P,P,32) channels-last ----------------
__global__ void maxpool_cl_k(const float* __restrict__ x, float* __restrict__ xp){
  int idx = blockIdx.x*256 + threadIdx.x;   // b*NP + pix
  if (idx >= BATCH*NP) return;
  int wp = idx & (P-1); int t = idx >> 7; int hp = t & (P-1); int b = t >> 7;
  const float* src = x + ((size_t)b*32*65536) + (size_t)(hp*2)*256 + wp*2;
  float m[32];
  #pragma unroll
  for (int c = 0; c < 32; c++){
    const float* s = src + (size_t)c*65536;
    m[c] = fmaxf(fmaxf(s[0], s[1]), fmaxf(s[256], s[257]));
  }
  float* dst = xp + (size_t)idx*32;
  #pragma unroll
  for (int q = 0; q < 8; q++) *(float4*)(dst + q*4) = *(float4*)(m + q*4);
}

// ---------------- fused weight prep (all bf16 transposes) ----------------
__global__ void wprep_all_k(const float* __restrict__ wg, const float* __restrict__ w1,
                            const float* __restrict__ w2, const float* __restrict__ wo1,
                            const float* __restrict__ wo2,
                            short* __restrict__ wT, short* __restrict__ wd1T,
                            short* __restrict__ wd2T, short* __restrict__ woT1,
                            short* __restrict__ woT2){
  int idx = blockIdx.x*256 + threadIdx.x;
  if (idx < 294912){
    int cin = idx & 127; int t = idx >> 7; int gidx = t & 255; int tap = t >> 8;
    int ch = gidx >> 2, gate = gidx & 3;
    wT[idx] = f2bf(wg[((size_t)(gate*64 + ch)*128 + cin)*9 + tap]);
    return;
  }
  idx -= 294912;
  if (idx < 18432){
    int c = idx & 31; int t = idx >> 5; int o = t & 63; int tap = t >> 6;
    wd1T[idx] = f2bf(w1[(size_t)(o*32 + c)*9 + tap]);
    return;
  }
  idx -= 18432;
  if (idx < 36864){
    int c = idx & 63; int t = idx >> 6; int o = t & 63; int tap = t >> 6;
    wd2T[idx] = f2bf(w2[(size_t)(o*64 + c)*9 + tap]);
    return;
  }
  idx -= 36864;
  if (idx < 9216){
    int c = idx & 31; int t = idx >> 5; int o = t & 31; int tap = t >> 5;
    woT1[idx] = (o < 18) ? f2bf(wo1[(size_t)(o*32 + c)*9 + tap]) : (short)0;
    return;
  }
  idx -= 9216;
  if (idx < 18432){
    int c = idx & 63; int t = idx >> 6; int o = t & 31; int tap = t >> 5;
    woT2[idx] = (o < 18) ? f2bf(wo2[(size_t)(o*64 + c)*9 + tap]) : (short)0;
  }
}

// ---------------- offset conv as MFMA: channels-last in, planar 18-ch out ----------------
template<int CIN>
__global__ __launch_bounds__(256) void offconv_mfma_k(
    const float* __restrict__ incl, const short* __restrict__ woT,
    const float* __restrict__ bias, float* __restrict__ off_out){
  const int ROWB = CIN*2;
  const int PMASK = CIN/8 - 1;
  __shared__ short xs[180*CIN];
  int tid = threadIdx.x;
  int tile = blockIdx.x, b = blockIdx.y;
  int tx0 = (tile & 7)*16, ty0 = (tile >> 3)*8;
  const float* inb = incl + (size_t)b*NP*CIN;
  for (int e = tid; e < 180*(CIN/8); e += 256){
    int p = e % 180, cg = e / 180;
    int hr = p/18, wc = p%18;
    int gy = ty0 + hr - 1, gx = tx0 + wc - 1;
    bool ok = ((unsigned)gy < P) && ((unsigned)gx < P);
    union { short s[8]; bf16x8 v; } u;
    if (ok){
      const float* src = inb + ((size_t)gy*P + gx)*CIN + cg*8;
      float4 a = *(const float4*)src, bb = *(const float4*)(src+4);
      u.s[0]=f2bf(a.x); u.s[1]=f2bf(a.y); u.s[2]=f2bf(a.z); u.s[3]=f2bf(a.w);
      u.s[4]=f2bf(bb.x); u.s[5]=f2bf(bb.y); u.s[6]=f2bf(bb.z); u.s[7]=f2bf(bb.w);
    } else {
      #pragma unroll
      for (int j = 0; j < 8; j++) u.s[j] = 0;
    }
    int boff = p*ROWB + ((cg*16) ^ ((p & PMASK)<<4));
    *(bf16x8*)((char*)xs + boff) = u.v;
  }
  __syncthreads();
  int lane = tid & 63, wid = tid >> 6;
  int kg = lane >> 4, ln = lane & 15;
  f32x4 acc[2][2];
  #pragma unroll
  for (int mf = 0; mf < 2; mf++)
    #pragma unroll
    for (int r = 0; r < 2; r++) acc[mf][r] = (f32x4){0.f,0.f,0.f,0.f};
  #pragma unroll
  for (int tap = 0; tap < 9; tap++){
    const int ky = tap/3, kx = tap%3;
    #pragma unroll
    for (int cb = 0; cb < CIN/32; cb++){
      bf16x8 af[2];
      #pragma unroll
      for (int mf = 0; mf < 2; mf++)
        af[mf] = *(const bf16x8*)(woT + ((size_t)(tap*32 + mf*16 + ln)*CIN + cb*32 + kg*8));
      #pragma unroll
      for (int r = 0; r < 2; r++){
        int p = (wid*2 + r + ky)*18 + ln + kx;
        int boff = p*ROWB + ((cb*64 + kg*16) ^ ((p & PMASK)<<4));
        bf16x8 bfv = *(const bf16x8*)((const char*)xs + boff);
        #pragma unroll
        for (int mf = 0; mf < 2; mf++)
          acc[mf][r] = __builtin_amdgcn_mfma_f32_16x16x32_bf16(af[mf], bfv, acc[mf][r], 0, 0, 0);
      }
    }
  }
  #pragma unroll
  for (int mf = 0; mf < 2; mf++){
    #pragma unroll
    for (int r = 0; r < 2; r++){
      int py = ty0 + wid*2 + r, px = tx0 + ln;
      #pragma unroll
      for (int j = 0; j < 4; j++){
        int o = mf*16 + kg*4 + j;
        if (o < 18)
          off_out[((size_t)(b*18 + o))*NP + py*P + px] = acc[mf][r][j] + bias[o];
      }
    }
  }
}

// ---------------- deformable conv as MFMA ----------------
template<int CIN>
__global__ __launch_bounds__(256) void deform_mfma_k(
    const float* __restrict__ incl, const float* __restrict__ off,
    const short* __restrict__ wdT, float* __restrict__ outcl){
  const int ROWB = CIN*2;
  const int PMASK = CIN/8 - 1;
  __shared__ short s_lds[128*CIN];
  int tid = threadIdx.x;
  int tile = blockIdx.x, b = blockIdx.y;
  int tx0 = (tile & 7)*16, ty0 = (tile >> 3)*8;
  int lane = tid & 63, wid = tid >> 6;
  int kg = lane >> 4, ln = lane & 15;
  int sp = tid & 127, shalf = tid >> 7;
  int spx = sp & 15, spy = sp >> 4;
  int gy = ty0 + spy, gx = tx0 + spx;
  const float* inb = incl + (size_t)b*NP*CIN;
  const float* offb = off + (size_t)b*18*NP + gy*P + gx;
  f32x4 acc[4][2];
  #pragma unroll
  for (int mf = 0; mf < 4; mf++)
    #pragma unroll
    for (int r = 0; r < 2; r++) acc[mf][r] = (f32x4){0.f,0.f,0.f,0.f};

  for (int tap = 0; tap < 9; tap++){
    float dy = offb[(size_t)tap*NP], dx = offb[(size_t)(9+tap)*NP];
    float ys = (float)gy + (float)(tap/3 - 1) + dy;
    float xsm = (float)gx + (float)(tap%3 - 1) + dx;
    float y0f = floorf(ys), x0f = floorf(xsm);
    float wy1 = ys - y0f, wx1 = xsm - x0f;
    float wy0 = 1.f - wy1, wx0 = 1.f - wx1;
    int y0 = (int)y0f, x0 = (int)x0f;
    int y1i = y0 + 1, x1i = x0 + 1;
    bool v0y = ((unsigned)y0 < P), v1y = ((unsigned)y1i < P);
    bool v0x = ((unsigned)x0 < P), v1x = ((unsigned)x1i < P);
    float w00 = (v0y && v0x) ? wy0*wx0 : 0.f;
    float w01 = (v0y && v1x) ? wy0*wx1 : 0.f;
    float w10 = (v1y && v0x) ? wy1*wx0 : 0.f;
    float w11 = (v1y && v1x) ? wy1*wx1 : 0.f;
    int yc0 = min(max(y0,0),P-1), yc1 = min(max(y1i,0),P-1);
    int xc0 = min(max(x0,0),P-1), xc1 = min(max(x1i,0),P-1);
    const float* p00 = inb + ((size_t)yc0*P + xc0)*CIN;
    const float* p01 = inb + ((size_t)yc0*P + xc1)*CIN;
    const float* p10 = inb + ((size_t)yc1*P + xc0)*CIN;
    const float* p11 = inb + ((size_t)yc1*P + xc1)*CIN;
    __syncthreads();
    #pragma unroll
    for (int it = 0; it < CIN/16; it++){
      int c0 = shalf*(CIN/2) + it*8;
      float4 a0 = *(const float4*)(p00 + c0), a1 = *(const float4*)(p00 + c0 + 4);
      float4 b0 = *(const float4*)(p01 + c0), b1 = *(const float4*)(p01 + c0 + 4);
      float4 c0v = *(const float4*)(p10 + c0), c1v = *(const float4*)(p10 + c0 + 4);
      float4 d0 = *(const float4*)(p11 + c0), d1 = *(const float4*)(p11 + c0 + 4);
      union { short s[8]; bf16x8 v; } u;
      u.s[0] = f2bf(w00*a0.x + w01*b0.x + w10*c0v.x + w11*d0.x);
      u.s[1] = f2bf(w00*a0.y + w01*b0.y + w10*c0v.y + w11*d0.y);
      u.s[2] = f2bf(w00*a0.z + w01*b0.z + w10*c0v.z + w11*d0.z);
      u.s[3] = f2bf(w00*a0.w + w01*b0.w + w10*c0v.w + w11*d0.w);
      u.s[4] = f2bf(w00*a1.x + w01*b1.x + w10*c1v.x + w11*d1.x);
      u.s[5] = f2bf(w00*a1.y + w01*b1.y + w10*c1v.y + w11*d1.y);
      u.s[6] = f2bf(w00*a1.z + w01*b1.z + w10*c1v.z + w11*d1.z);
      u.s[7] = f2bf(w00*a1.w + w01*b1.w + w10*c1v.w + w11*d1.w);
      int boff = sp*ROWB + ((c0*2) ^ ((sp & PMASK)<<4));
      *(bf16x8*)((char*)s_lds + boff) = u.v;
    }
    __syncthreads();
    #pragma unroll
    for (int cb = 0; cb < CIN/32; cb++){
      bf16x8 af[4];
      #pragma unroll
      for (int mf = 0; mf < 4; mf++)
        af[mf] = *(const bf16x8*)(wdT + ((size_t)(tap*64 + mf*16 + ln)*CIN + cb*32 + kg*8));
      #pragma unroll
      for (int r = 0; r < 2; r++){
        int p = (wid*2 + r)*16 + ln;
        int boff = p*ROWB + ((cb*64 + kg*16) ^ ((p & PMASK)<<4));
        bf16x8 bfv = *(const bf16x8*)((const char*)s_lds + boff);
        #pragma unroll
        for (int mf = 0; mf < 4; mf++)
          acc[mf][r] = __builtin_amdgcn_mfma_f32_16x16x32_bf16(af[mf], bfv, acc[mf][r], 0, 0, 0);
      }
    }
  }
  #pragma unroll
  for (int mf = 0; mf < 4; mf++){
    #pragma unroll
    for (int r = 0; r < 2; r++){
      int py = ty0 + wid*2 + r, px = tx0 + ln;
      float* dst = outcl + ((size_t)b*NP + (size_t)py*P + px)*64 + mf*16 + kg*4;
      *(f32x4*)dst = acc[mf][r];
    }
  }
}

// ---------------- BN stats ----------------
__global__ void bnsum_k(const float* __restrict__ y, float* __restrict__ part){
  int lane = threadIdx.x & 63, wid = threadIdx.x >> 6;
  float s = 0.f, sq = 0.f;
  for (int pix = blockIdx.x*4 + wid; pix < BATCH*NP; pix += 256){
    float v = y[(size_t)pix*64 + lane];
    s += v; sq += v*v;
  }
  __shared__ float red[4][128];
  red[wid][lane] = s; red[wid][64+lane] = sq;
  __syncthreads();
  if (wid == 0){
    float S = red[0][lane]+red[1][lane]+red[2][lane]+red[3][lane];
    float Q = red[0][64+lane]+red[1][64+lane]+red[2][64+lane]+red[3][64+lane];
    part[blockIdx.x*128 + lane] = S;
    part[blockIdx.x*128 + 64 + lane] = Q;
  }
}

__global__ void bnfinal_k(const float* __restrict__ part, const float* __restrict__ g,
                          const float* __restrict__ be, float* __restrict__ stats){
  int ch = threadIdx.x;
  float S = 0.f, Q = 0.f;
  for (int i = 0; i < 64; i++){ S += part[i*128 + ch]; Q += part[i*128 + 64 + ch]; }
  const float inv = 1.f/(float)(BATCH*NP);
  float mean = S*inv;
  float var = Q*inv - mean*mean;
  float scale = rsqrtf(var + 1e-5f)*g[ch];
  stats[ch] = scale;
  stats[64+ch] = be[ch] - mean*scale;
}

// BN apply + relu, fp32 in-place (y1 path)
__global__ void bnapply_cl_k(float* __restrict__ y, const float* __restrict__ stats){
  int idx = blockIdx.x*256 + threadIdx.x;
  if (idx >= BATCH*NP*16) return;
  int ch4 = (idx & 15)*4;
  float4 v = ((float4*)y)[idx];
  v.x = fmaxf(v.x*stats[ch4+0] + stats[64+ch4+0], 0.f);
  v.y = fmaxf(v.y*stats[ch4+1] + stats[64+ch4+1], 0.f);
  v.z = fmaxf(v.z*stats[ch4+2] + stats[64+ch4+2], 0.f);
  v.w = fmaxf(v.w*stats[ch4+3] + stats[64+ch4+3], 0.f);
  ((float4*)y)[idx] = v;
}

// BN apply + relu, y2 fp32 -> xh bf16 slots [0:64] of 128
__global__ void bnapply_bf16_k(const float* __restrict__ y, const float* __restrict__ stats,
                               short* __restrict__ xh){
  int idx = blockIdx.x*256 + threadIdx.x;   // B*NP*8 groups of 8 ch
  if (idx >= BATCH*NP*8) return;
  int u8 = (idx & 7)*8; int pix = idx >> 3;
  const float* src = y + (size_t)pix*64 + u8;
  float4 a = *(const float4*)src, b4 = *(const float4*)(src+4);
  union { short s[8]; bf16x8 v; } o;
  o.s[0] = f2bf(fmaxf(a.x*stats[u8+0] + stats[64+u8+0], 0.f));
  o.s[1] = f2bf(fmaxf(a.y*stats[u8+1] + stats[64+u8+1], 0.f));
  o.s[2] = f2bf(fmaxf(a.z*stats[u8+2] + stats[64+u8+2], 0.f));
  o.s[3] = f2bf(fmaxf(a.w*stats[u8+3] + stats[64+u8+3], 0.f));
  o.s[4] = f2bf(fmaxf(b4.x*stats[u8+4] + stats[64+u8+4], 0.f));
  o.s[5] = f2bf(fmaxf(b4.y*stats[u8+5] + stats[64+u8+5], 0.f));
  o.s[6] = f2bf(fmaxf(b4.z*stats[u8+6] + stats[64+u8+6], 0.f));
  o.s[7] = f2bf(fmaxf(b4.w*stats[u8+7] + stats[64+u8+7], 0.f));
  *(bf16x8*)(xh + (size_t)pix*128 + u8) = o.v;
}

// h0 planar -> xh bf16 slots [64:128] (64ch x 64px LDS transpose)
__global__ void h2cl_k(const float* __restrict__ h0, short* __restrict__ xh){
  __shared__ float t[64][65];
  int b = blockIdx.y;
  int p0 = blockIdx.x*64;
  int pl = threadIdx.x & 63;
  int cq = threadIdx.x >> 6;
  const float* src = h0 + (size_t)b*64*NP + p0 + pl;
  #pragma unroll
  for (int i = 0; i < 16; i++)
    t[cq*16+i][pl] = src[(size_t)(cq*16+i)*NP];
  __syncthreads();
  int p = threadIdx.x >> 2, q = threadIdx.x & 3;
  short* dst = xh + ((size_t)(b*NP + p0 + p))*128 + 64 + q*16;
  union { short s[8]; bf16x8 v; } o0, o1;
  #pragma unroll
  for (int i = 0; i < 8; i++){ o0.s[i] = f2bf(t[q*16+i][p]); o1.s[i] = f2bf(t[q*16+8+i][p]); }
  *(bf16x8*)dst = o0.v;
  *(bf16x8*)(dst+8) = o1.v;
}

// ---------------- gates conv (128->256) MFMA + fused LSTM, A staged in LDS per tap ----------------
// grid (64 tiles of 16x16 px, B); block 512 = 8 waves (wave: ct = wid>>1, row-half = wid&1).
__global__ __launch_bounds__(512, 2) void gates_mfma_k(
    const short* __restrict__ xh, const float* __restrict__ c0,
    const short* __restrict__ wT, const float* __restrict__ bg,
    float* __restrict__ outh, float* __restrict__ outc){
  extern __shared__ short lds[];
  short* bs = lds;             // 324 px x 256B (swizzled) = 82944 B
  short* as = lds + 324*128;   // 256 rows x 256B (swizzled) = 65536 B
  int tid = threadIdx.x;
  int tile = blockIdx.x, b = blockIdx.y;
  int tx0 = (tile & 7)*16, ty0 = (tile >> 3)*16;

  // ---- stage B tile: 18x18 halo x 128 ch bf16, coalesced (16 thr/pixel) ----
  const short* xb = xh + (size_t)b*NP*128;
  for (int e = tid; e < 324*16; e += 512){
    int cg = e & 15, p = e >> 4;
    int hr = p/18, wc = p - hr*18;
    int gy = ty0 + hr - 1, gx = tx0 + wc - 1;
    bf16x8 v;
    if (((unsigned)gy < P) && ((unsigned)gx < P))
      v = *(const bf16x8*)(xb + ((size_t)gy*P + gx)*128 + cg*8);
    else
      v = (bf16x8){0,0,0,0,0,0,0,0};
    *(bf16x8*)((char*)bs + p*256 + ((cg*16) ^ ((p&7)<<4))) = v;
  }

  int lane = tid & 63, wid = tid >> 6;
  int kg = lane >> 4, ln = lane & 15;
  int ct = wid >> 1, rh = wid & 1;
  f32x4 acc[4][8];
  #pragma unroll
  for (int mf = 0; mf < 4; mf++)
    #pragma unroll
    for (int rr = 0; rr < 8; rr++) acc[mf][rr] = (f32x4){0.f,0.f,0.f,0.f};

  for (int tap = 0; tap < 9; tap++){
    __syncthreads();   // prev tap's A reads done (tap0: B staging done)
    const short* wsrc = wT + (size_t)tap*(256*128);
    for (int e = tid; e < 256*16; e += 512){
      int cg = e & 15, rw = e >> 4;
      *(bf16x8*)((char*)as + rw*256 + ((cg*16) ^ ((rw&7)<<4))) =
          *(const bf16x8*)(wsrc + rw*128 + cg*8);
    }
    __syncthreads();
    int ky = tap/3, kx = tap - ky*3;
    #pragma unroll
    for (int cb = 0; cb < 4; cb++){
      bf16x8 af[4];
      #pragma unroll
      for (int mf = 0; mf < 4; mf++){
        int rw = ct*64 + mf*16 + ln;
        af[mf] = *(const bf16x8*)((const char*)as + rw*256 + ((cb*64 + kg*16) ^ ((rw&7)<<4)));
      }
      #pragma unroll
      for (int rr = 0; rr < 8; rr++){
        int p = (rh*8 + rr + ky)*18 + ln + kx;
        bf16x8 bfv = *(const bf16x8*)((const char*)bs + p*256 + ((cb*64 + kg*16) ^ ((p&7)<<4)));
        #pragma unroll
        for (int mf = 0; mf < 4; mf++)
          acc[mf][rr] = __builtin_amdgcn_mfma_f32_16x16x32_bf16(af[mf], bfv, acc[mf][rr], 0, 0, 0);
      }
    }
  }

  // epilogue: acc[mf][rr] regs j=0..3 = (i,f,o,g) for channel ct*16+mf*4+kg
  #pragma unroll
  for (int mf = 0; mf < 4; mf++){
    int ch = ct*16 + mf*4 + kg;
    float bi = bg[ch], bff = bg[64+ch], bo = bg[128+ch], bgv = bg[192+ch];
    #pragma unroll
    for (int rr = 0; rr < 8; rr++){
      int py = ty0 + rh*8 + rr, px = tx0 + ln;
      size_t pidx = ((size_t)(b*64 + ch))*NP + (size_t)py*P + px;
      f32x4 a = acc[mf][rr];
      float cv = sigmoidf_(a[1]+bff)*c0[pidx] + sigmoidf_(a[0]+bi)*tanhf(a[3]+bgv);
      float hv = sigmoidf_(a[2]+bo)*tanhf(cv);
      outh[pidx] = hv;
      outc[pidx] = cv;
    }
  }
}

extern "C" void kernel_launch(void* const* d_in, const int* in_sizes, int n_in,
                              void* d_out, int out_size, void* d_ws, size_t ws_size,
                              hipStream_t stream) {
  const float* x      = (const float*)d_in[0];
  const float* h0     = (const float*)d_in[1];
  const float* c0     = (const float*)d_in[2];
  const float* w_off1 = (const float*)d_in[3];
  const float* b_off1 = (const float*)d_in[4];
  const float* w1     = (const float*)d_in[5];
  const float* g1     = (const float*)d_in[6];
  const float* be1    = (const float*)d_in[7];
  const float* w_off2 = (const float*)d_in[8];
  const float* b_off2 = (const float*)d_in[9];
  const float* w2     = (const float*)d_in[10];
  const float* g2     = (const float*)d_in[11];
  const float* be2    = (const float*)d_in[12];
  const float* wg     = (const float*)d_in[13];
  const float* bg     = (const float*)d_in[14];

  float* ws    = (float*)d_ws;
  // layout (floats): y2 | xh(bf16, 4.19M floats, OVERLAYS xpcl+off+y1 head) ...
  float* y2    = ws;                          // 4194304
  short* xh    = (short*)(ws + 4194304);      // 8388608 shorts = 4194304 floats
  float* xpcl  = ws + 4194304;                // 2097152 (dead before xh written)
  float* off   = ws + 4194304 + 2097152;      // 1179648 (dead before xh written)
  float* y1    = ws + 4194304 + 3276800;      // 4194304 (head overlapped by xh tail; dead first)
  float* part  = ws + 11665408;               // 8192
  float* stats = ws + 11673600;               // 128
  short* wT    = (short*)(ws + 11673728);     // 294912
  short* wd1T  = wT + 294912;                 // 18432
  short* wd2T  = wd1T + 18432;                // 36864
  short* woT1  = wd2T + 36864;                // 9216
  short* woT2  = woT1 + 9216;                 // 18432

  (void)hipFuncSetAttribute((const void*)gates_mfma_k,
                            hipFuncAttributeMaxDynamicSharedMemorySize, 148480);

  maxpool_cl_k<<<dim3((BATCH*NP + 255)/256), dim3(256), 0, stream>>>(x, xpcl);
  wprep_all_k<<<dim3((377856 + 255)/256), dim3(256), 0, stream>>>(
      wg, w1, w2, w_off1, w_off2, wT, wd1T, wd2T, woT1, woT2);

  offconv_mfma_k<32><<<dim3(128, BATCH), dim3(256), 0, stream>>>(xpcl, woT1, b_off1, off);
  deform_mfma_k<32><<<dim3(128, BATCH), dim3(256), 0, stream>>>(xpcl, off, wd1T, y1);
  bnsum_k<<<dim3(64), dim3(256), 0, stream>>>(y1, part);
  bnfinal_k<<<dim3(1), dim3(64), 0, stream>>>(part, g1, be1, stats);
  bnapply_cl_k<<<dim3((BATCH*NP*16 + 255)/256), dim3(256), 0, stream>>>(y1, stats);

  offconv_mfma_k<64><<<dim3(128, BATCH), dim3(256), 0, stream>>>(y1, woT2, b_off2, off);
  deform_mfma_k<64><<<dim3(128, BATCH), dim3(256), 0, stream>>>(y1, off, wd2T, y2);
  // xpcl/off/y1 dead from here: xh overlay becomes writable
  h2cl_k<<<dim3(NP/64, BATCH), dim3(256), 0, stream>>>(h0, xh);
  bnsum_k<<<dim3(64), dim3(256), 0, stream>>>(y2, part);
  bnfinal_k<<<dim3(1), dim3(64), 0, stream>>>(part, g2, be2, stats);
  bnapply_bf16_k<<<dim3((BATCH*NP*8 + 255)/256), dim3(256), 0, stream>>>(y2, stats, xh);

  float* outh = (float*)d_out;
  float* outc = outh + (size_t)BATCH*64*NP;
  gates_mfma_k<<<dim3(64, BATCH), dim3(512), 148480, stream>>>(xh, c0, wT, bg, outh, outc);
}

// Round 5
// 299.001 us; speedup vs baseline: 8.7401x; 1.2693x over previous
//
#include <hip/hip_runtime.h>
#include <math.h>

#define P 128
#define NP (P*P)
#define BATCH 4

typedef __attribute__((ext_vector_type(8))) short bf16x8;
typedef __attribute__((ext_vector_type(4))) float f32x4;

__device__ __forceinline__ float sigmoidf_(float x){ return 1.f/(1.f+__expf(-x)); }
__device__ __forceinline__ short f2bf(float f){
  unsigned u = __builtin_bit_cast(unsigned, f);
  u = (u + 0x7FFFu + ((u>>16)&1u)) >> 16;
  return (short)u;
}
__device__ __forceinline__ float bf2f(short s){
  unsigned u = ((unsigned)(unsigned short)s) << 16;
  return __builtin_bit_cast(float, u);
}

// ---------------- maxpool 2x2 stride 2: (B,32,256,256) planar -> (B,P,P,32) channels-last ----------------
__global__ void maxpool_cl_k(const float* __restrict__ x, float* __restrict__ xp){
  int idx = blockIdx.x*256 + threadIdx.x;   // b*NP + pix
  if (idx >= BATCH*NP) return;
  int wp = idx & (P-1); int t = idx >> 7; int hp = t & (P-1); int b = t >> 7;
  const float* src = x + ((size_t)b*32*65536) + (size_t)(hp*2)*256 + wp*2;
  float m[32];
  #pragma unroll
  for (int c = 0; c < 32; c++){
    const float* s = src + (size_t)c*65536;
    m[c] = fmaxf(fmaxf(s[0], s[1]), fmaxf(s[256], s[257]));
  }
  float* dst = xp + (size_t)idx*32;
  #pragma unroll
  for (int q = 0; q < 8; q++) *(float4*)(dst + q*4) = *(float4*)(m + q*4);
}

// ---------------- fused weight prep (all bf16 transposes) ----------------
__global__ void wprep_all_k(const float* __restrict__ wg, const float* __restrict__ w1,
                            const float* __restrict__ w2, const float* __restrict__ wo1,
                            const float* __restrict__ wo2,
                            short* __restrict__ wT, short* __restrict__ wd1T,
                            short* __restrict__ wd2T, short* __restrict__ woT1,
                            short* __restrict__ woT2){
  int idx = blockIdx.x*256 + threadIdx.x;
  if (idx < 294912){
    int cin = idx & 127; int t = idx >> 7; int gidx = t & 255; int tap = t >> 8;
    int ch = gidx >> 2, gate = gidx & 3;
    wT[idx] = f2bf(wg[((size_t)(gate*64 + ch)*128 + cin)*9 + tap]);
    return;
  }
  idx -= 294912;
  if (idx < 18432){
    int c = idx & 31; int t = idx >> 5; int o = t & 63; int tap = t >> 6;
    wd1T[idx] = f2bf(w1[(size_t)(o*32 + c)*9 + tap]);
    return;
  }
  idx -= 18432;
  if (idx < 36864){
    int c = idx & 63; int t = idx >> 6; int o = t & 63; int tap = t >> 6;
    wd2T[idx] = f2bf(w2[(size_t)(o*64 + c)*9 + tap]);
    return;
  }
  idx -= 36864;
  if (idx < 9216){
    int c = idx & 31; int t = idx >> 5; int o = t & 31; int tap = t >> 5;
    woT1[idx] = (o < 18) ? f2bf(wo1[(size_t)(o*32 + c)*9 + tap]) : (short)0;
    return;
  }
  idx -= 9216;
  if (idx < 18432){
    int c = idx & 63; int t = idx >> 6; int o = t & 31; int tap = t >> 5;
    woT2[idx] = (o < 18) ? f2bf(wo2[(size_t)(o*64 + c)*9 + tap]) : (short)0;
  }
}

// ---------------- offset conv as MFMA: channels-last in, planar 18-ch out ----------------
template<int CIN>
__global__ __launch_bounds__(256) void offconv_mfma_k(
    const float* __restrict__ incl, const short* __restrict__ woT,
    const float* __restrict__ bias, float* __restrict__ off_out){
  const int ROWB = CIN*2;
  const int PMASK = CIN/8 - 1;
  const int CG = CIN/8, CGS = (CIN==64)?3:2;
  __shared__ short xs[180*CIN];
  int tid = threadIdx.x;
  int tile = blockIdx.x, b = blockIdx.y;
  int tx0 = (tile & 7)*16, ty0 = (tile >> 3)*8;
  const float* inb = incl + (size_t)b*NP*CIN;
  for (int e = tid; e < 180*CG; e += 256){
    int cg = e & (CG-1), p = e >> CGS;   // cg fastest -> coalesced 256B/64-px groups
    int hr = p/18, wc = p - hr*18;
    int gy = ty0 + hr - 1, gx = tx0 + wc - 1;
    bool ok = ((unsigned)gy < P) && ((unsigned)gx < P);
    union { short s[8]; bf16x8 v; } u;
    if (ok){
      const float* src = inb + ((size_t)gy*P + gx)*CIN + cg*8;
      float4 a = *(const float4*)src, bb = *(const float4*)(src+4);
      u.s[0]=f2bf(a.x); u.s[1]=f2bf(a.y); u.s[2]=f2bf(a.z); u.s[3]=f2bf(a.w);
      u.s[4]=f2bf(bb.x); u.s[5]=f2bf(bb.y); u.s[6]=f2bf(bb.z); u.s[7]=f2bf(bb.w);
    } else {
      #pragma unroll
      for (int j = 0; j < 8; j++) u.s[j] = 0;
    }
    int boff = p*ROWB + ((cg*16) ^ ((p & PMASK)<<4));
    *(bf16x8*)((char*)xs + boff) = u.v;
  }
  __syncthreads();
  int lane = tid & 63, wid = tid >> 6;
  int kg = lane >> 4, ln = lane & 15;
  f32x4 acc[2][2];
  #pragma unroll
  for (int mf = 0; mf < 2; mf++)
    #pragma unroll
    for (int r = 0; r < 2; r++) acc[mf][r] = (f32x4){0.f,0.f,0.f,0.f};
  #pragma unroll
  for (int tap = 0; tap < 9; tap++){
    const int ky = tap/3, kx = tap%3;
    #pragma unroll
    for (int cb = 0; cb < CIN/32; cb++){
      bf16x8 af[2];
      #pragma unroll
      for (int mf = 0; mf < 2; mf++)
        af[mf] = *(const bf16x8*)(woT + ((size_t)(tap*32 + mf*16 + ln)*CIN + cb*32 + kg*8));
      #pragma unroll
      for (int r = 0; r < 2; r++){
        int p = (wid*2 + r + ky)*18 + ln + kx;
        int boff = p*ROWB + ((cb*64 + kg*16) ^ ((p & PMASK)<<4));
        bf16x8 bfv = *(const bf16x8*)((const char*)xs + boff);
        #pragma unroll
        for (int mf = 0; mf < 2; mf++)
          acc[mf][r] = __builtin_amdgcn_mfma_f32_16x16x32_bf16(af[mf], bfv, acc[mf][r], 0, 0, 0);
      }
    }
  }
  #pragma unroll
  for (int mf = 0; mf < 2; mf++){
    #pragma unroll
    for (int r = 0; r < 2; r++){
      int py = ty0 + wid*2 + r, px = tx0 + ln;
      #pragma unroll
      for (int j = 0; j < 4; j++){
        int o = mf*16 + kg*4 + j;
        if (o < 18)
          off_out[((size_t)(b*18 + o))*NP + py*P + px] = acc[mf][r][j] + bias[o];
      }
    }
  }
}

// ---------------- deformable conv as MFMA: x-tile (+/-3 halo) in LDS, register-direct sampling ----------------
// grid (256 tiles of 8x8 px, B); block 256 = 4 waves; wave w owns px rows 2w..2w+1 (16 px).
template<int CIN>
__global__ __launch_bounds__(256) void deform_mfma_k(
    const float* __restrict__ incl, const float* __restrict__ off,
    const short* __restrict__ wdT, float* __restrict__ outcl){
  const int HS = 14, NHP = HS*HS;       // 8+2*3 halo side
  const int ROWB = CIN*2;
  const int CG = CIN/8, CGS = (CIN==64)?3:2;
  const int PM = (CIN==64)?7:3;         // swizzle mask must stay within row
  __shared__ short xt[NHP*CIN];
  int tid = threadIdx.x;
  int tile = blockIdx.x, b = blockIdx.y;
  int tx0 = (tile & 15)*8, ty0 = (tile >> 4)*8;
  const float* inb = incl + (size_t)b*NP*CIN;
  // stage halo tile fp32 -> bf16, cg-fastest (coalesced)
  for (int e = tid; e < NHP*CG; e += 256){
    int cg = e & (CG-1), p = e >> CGS;
    int hr = p/HS, wc = p - hr*HS;
    int gy = ty0 + hr - 3, gx = tx0 + wc - 3;
    union { short s[8]; bf16x8 v; } u;
    if (((unsigned)gy < P) && ((unsigned)gx < P)){
      const float* src = inb + ((size_t)gy*P + gx)*CIN + cg*8;
      float4 a = *(const float4*)src, bb = *(const float4*)(src+4);
      u.s[0]=f2bf(a.x); u.s[1]=f2bf(a.y); u.s[2]=f2bf(a.z); u.s[3]=f2bf(a.w);
      u.s[4]=f2bf(bb.x); u.s[5]=f2bf(bb.y); u.s[6]=f2bf(bb.z); u.s[7]=f2bf(bb.w);
    } else {
      #pragma unroll
      for (int j = 0; j < 8; j++) u.s[j] = 0;
    }
    *(bf16x8*)((char*)xt + p*ROWB + ((cg*16) ^ ((p & PM)<<4))) = u.v;
  }
  __syncthreads();

  int lane = tid & 63, wid = tid >> 6;
  int kg = lane >> 4, ln = lane & 15;
  int py = ty0 + wid*2 + (ln>>3), pxg = tx0 + (ln&7);
  const float* offb = off + (size_t)b*18*NP + (size_t)py*P + pxg;
  f32x4 acc[4];
  #pragma unroll
  for (int mf = 0; mf < 4; mf++) acc[mf] = (f32x4){0.f,0.f,0.f,0.f};

  for (int tap = 0; tap < 9; tap++){
    float dy = offb[(size_t)tap*NP], dx = offb[(size_t)(9+tap)*NP];
    float ys = (float)(py + tap/3 - 1) + dy;
    float xs = (float)(pxg + tap%3 - 1) + dx;
    float y0f = floorf(ys), x0f = floorf(xs);
    float wy1 = ys - y0f, wx1 = xs - x0f;
    float wy0 = 1.f - wy1, wx0 = 1.f - wx1;
    int y0 = (int)y0f, x0 = (int)x0f;
    bool v0y = ((unsigned)y0 < P), v1y = ((unsigned)(y0+1) < P);
    bool v0x = ((unsigned)x0 < P), v1x = ((unsigned)(x0+1) < P);
    float w00 = (v0y && v0x) ? wy0*wx0 : 0.f;
    float w01 = (v0y && v1x) ? wy0*wx1 : 0.f;
    float w10 = (v1y && v0x) ? wy1*wx0 : 0.f;
    float w11 = (v1y && v1x) ? wy1*wx1 : 0.f;
    int ly0 = min(max(y0 - ty0 + 3, 0), HS-1);
    int ly1 = min(max(y0 + 1 - ty0 + 3, 0), HS-1);
    int lx0 = min(max(x0 - tx0 + 3, 0), HS-1);
    int lx1 = min(max(x0 + 1 - tx0 + 3, 0), HS-1);
    int p00 = ly0*HS + lx0, p01 = ly0*HS + lx1;
    int p10 = ly1*HS + lx0, p11 = ly1*HS + lx1;
    #pragma unroll
    for (int cb = 0; cb < CIN/32; cb++){
      int ko = (cb*32 + kg*8)*2;
      bf16x8 c00 = *(const bf16x8*)((const char*)xt + p00*ROWB + (ko ^ ((p00 & PM)<<4)));
      bf16x8 c01 = *(const bf16x8*)((const char*)xt + p01*ROWB + (ko ^ ((p01 & PM)<<4)));
      bf16x8 c10 = *(const bf16x8*)((const char*)xt + p10*ROWB + (ko ^ ((p10 & PM)<<4)));
      bf16x8 c11 = *(const bf16x8*)((const char*)xt + p11*ROWB + (ko ^ ((p11 & PM)<<4)));
      union { short s[8]; bf16x8 v; } bu;
      #pragma unroll
      for (int j = 0; j < 8; j++){
        float v = w00*bf2f(c00[j]) + w01*bf2f(c01[j]) + w10*bf2f(c10[j]) + w11*bf2f(c11[j]);
        bu.s[j] = f2bf(v);
      }
      #pragma unroll
      for (int mf = 0; mf < 4; mf++){
        bf16x8 af = *(const bf16x8*)(wdT + ((size_t)(tap*64 + mf*16 + ln)*CIN + cb*32 + kg*8));
        acc[mf] = __builtin_amdgcn_mfma_f32_16x16x32_bf16(af, bu.v, acc[mf], 0, 0, 0);
      }
    }
  }
  #pragma unroll
  for (int mf = 0; mf < 4; mf++){
    float* dst = outcl + ((size_t)b*NP + (size_t)py*P + pxg)*64 + mf*16 + kg*4;
    *(f32x4*)dst = acc[mf];
  }
}

// ---------------- BN stats ----------------
__global__ void bnsum_k(const float* __restrict__ y, float* __restrict__ part){
  int lane = threadIdx.x & 63, wid = threadIdx.x >> 6;
  float s = 0.f, sq = 0.f;
  for (int pix = blockIdx.x*4 + wid; pix < BATCH*NP; pix += 256){
    float v = y[(size_t)pix*64 + lane];
    s += v; sq += v*v;
  }
  __shared__ float red[4][128];
  red[wid][lane] = s; red[wid][64+lane] = sq;
  __syncthreads();
  if (wid == 0){
    float S = red[0][lane]+red[1][lane]+red[2][lane]+red[3][lane];
    float Q = red[0][64+lane]+red[1][64+lane]+red[2][64+lane]+red[3][64+lane];
    part[blockIdx.x*128 + lane] = S;
    part[blockIdx.x*128 + 64 + lane] = Q;
  }
}

__global__ void bnfinal_k(const float* __restrict__ part, const float* __restrict__ g,
                          const float* __restrict__ be, float* __restrict__ stats){
  int ch = threadIdx.x;
  float S = 0.f, Q = 0.f;
  for (int i = 0; i < 64; i++){ S += part[i*128 + ch]; Q += part[i*128 + 64 + ch]; }
  const float inv = 1.f/(float)(BATCH*NP);
  float mean = S*inv;
  float var = Q*inv - mean*mean;
  float scale = rsqrtf(var + 1e-5f)*g[ch];
  stats[ch] = scale;
  stats[64+ch] = be[ch] - mean*scale;
}

// BN apply + relu, fp32 in-place (y1 path)
__global__ void bnapply_cl_k(float* __restrict__ y, const float* __restrict__ stats){
  int idx = blockIdx.x*256 + threadIdx.x;
  if (idx >= BATCH*NP*16) return;
  int ch4 = (idx & 15)*4;
  float4 v = ((float4*)y)[idx];
  v.x = fmaxf(v.x*stats[ch4+0] + stats[64+ch4+0], 0.f);
  v.y = fmaxf(v.y*stats[ch4+1] + stats[64+ch4+1], 0.f);
  v.z = fmaxf(v.z*stats[ch4+2] + stats[64+ch4+2], 0.f);
  v.w = fmaxf(v.w*stats[ch4+3] + stats[64+ch4+3], 0.f);
  ((float4*)y)[idx] = v;
}

// BN apply + relu, y2 fp32 -> xh bf16 slots [0:64] of 128
__global__ void bnapply_bf16_k(const float* __restrict__ y, const float* __restrict__ stats,
                               short* __restrict__ xh){
  int idx = blockIdx.x*256 + threadIdx.x;   // B*NP*8 groups of 8 ch
  if (idx >= BATCH*NP*8) return;
  int u8 = (idx & 7)*8; int pix = idx >> 3;
  const float* src = y + (size_t)pix*64 + u8;
  float4 a = *(const float4*)src, b4 = *(const float4*)(src+4);
  union { short s[8]; bf16x8 v; } o;
  o.s[0] = f2bf(fmaxf(a.x*stats[u8+0] + stats[64+u8+0], 0.f));
  o.s[1] = f2bf(fmaxf(a.y*stats[u8+1] + stats[64+u8+1], 0.f));
  o.s[2] = f2bf(fmaxf(a.z*stats[u8+2] + stats[64+u8+2], 0.f));
  o.s[3] = f2bf(fmaxf(a.w*stats[u8+3] + stats[64+u8+3], 0.f));
  o.s[4] = f2bf(fmaxf(b4.x*stats[u8+4] + stats[64+u8+4], 0.f));
  o.s[5] = f2bf(fmaxf(b4.y*stats[u8+5] + stats[64+u8+5], 0.f));
  o.s[6] = f2bf(fmaxf(b4.z*stats[u8+6] + stats[64+u8+6], 0.f));
  o.s[7] = f2bf(fmaxf(b4.w*stats[u8+7] + stats[64+u8+7], 0.f));
  *(bf16x8*)(xh + (size_t)pix*128 + u8) = o.v;
}

// h0 planar -> xh bf16 slots [64:128] (64ch x 64px LDS transpose)
__global__ void h2cl_k(const float* __restrict__ h0, short* __restrict__ xh){
  __shared__ float t[64][65];
  int b = blockIdx.y;
  int p0 = blockIdx.x*64;
  int pl = threadIdx.x & 63;
  int cq = threadIdx.x >> 6;
  const float* src = h0 + (size_t)b*64*NP + p0 + pl;
  #pragma unroll
  for (int i = 0; i < 16; i++)
    t[cq*16+i][pl] = src[(size_t)(cq*16+i)*NP];
  __syncthreads();
  int p = threadIdx.x >> 2, q = threadIdx.x & 3;
  short* dst = xh + ((size_t)(b*NP + p0 + p))*128 + 64 + q*16;
  union { short s[8]; bf16x8 v; } o0, o1;
  #pragma unroll
  for (int i = 0; i < 8; i++){ o0.s[i] = f2bf(t[q*16+i][p]); o1.s[i] = f2bf(t[q*16+8+i][p]); }
  *(bf16x8*)dst = o0.v;
  *(bf16x8*)(dst+8) = o1.v;
}

// ---------------- gates conv (128->256) MFMA + fused LSTM, A staged in LDS per tap ----------------
__global__ __launch_bounds__(512, 2) void gates_mfma_k(
    const short* __restrict__ xh, const float* __restrict__ c0,
    const short* __restrict__ wT, const float* __restrict__ bg,
    float* __restrict__ outh, float* __restrict__ outc){
  extern __shared__ short lds[];
  short* bs = lds;             // 324 px x 256B (swizzled) = 82944 B
  short* as = lds + 324*128;   // 256 rows x 256B (swizzled) = 65536 B
  int tid = threadIdx.x;
  int tile = blockIdx.x, b = blockIdx.y;
  int tx0 = (tile & 7)*16, ty0 = (tile >> 3)*16;

  const short* xb = xh + (size_t)b*NP*128;
  for (int e = tid; e < 324*16; e += 512){
    int cg = e & 15, p = e >> 4;
    int hr = p/18, wc = p - hr*18;
    int gy = ty0 + hr - 1, gx = tx0 + wc - 1;
    bf16x8 v;
    if (((unsigned)gy < P) && ((unsigned)gx < P))
      v = *(const bf16x8*)(xb + ((size_t)gy*P + gx)*128 + cg*8);
    else
      v = (bf16x8){0,0,0,0,0,0,0,0};
    *(bf16x8*)((char*)bs + p*256 + ((cg*16) ^ ((p&7)<<4))) = v;
  }

  int lane = tid & 63, wid = tid >> 6;
  int kg = lane >> 4, ln = lane & 15;
  int ct = wid >> 1, rh = wid & 1;
  f32x4 acc[4][8];
  #pragma unroll
  for (int mf = 0; mf < 4; mf++)
    #pragma unroll
    for (int rr = 0; rr < 8; rr++) acc[mf][rr] = (f32x4){0.f,0.f,0.f,0.f};

  for (int tap = 0; tap < 9; tap++){
    __syncthreads();
    const short* wsrc = wT + (size_t)tap*(256*128);
    for (int e = tid; e < 256*16; e += 512){
      int cg = e & 15, rw = e >> 4;
      *(bf16x8*)((char*)as + rw*256 + ((cg*16) ^ ((rw&7)<<4))) =
          *(const bf16x8*)(wsrc + rw*128 + cg*8);
    }
    __syncthreads();
    int ky = tap/3, kx = tap - ky*3;
    #pragma unroll
    for (int cb = 0; cb < 4; cb++){
      bf16x8 af[4];
      #pragma unroll
      for (int mf = 0; mf < 4; mf++){
        int rw = ct*64 + mf*16 + ln;
        af[mf] = *(const bf16x8*)((const char*)as + rw*256 + ((cb*64 + kg*16) ^ ((rw&7)<<4)));
      }
      #pragma unroll
      for (int rr = 0; rr < 8; rr++){
        int p = (rh*8 + rr + ky)*18 + ln + kx;
        bf16x8 bfv = *(const bf16x8*)((const char*)bs + p*256 + ((cb*64 + kg*16) ^ ((p&7)<<4)));
        #pragma unroll
        for (int mf = 0; mf < 4; mf++)
          acc[mf][rr] = __builtin_amdgcn_mfma_f32_16x16x32_bf16(af[mf], bfv, acc[mf][rr], 0, 0, 0);
      }
    }
  }

  #pragma unroll
  for (int mf = 0; mf < 4; mf++){
    int ch = ct*16 + mf*4 + kg;
    float bi = bg[ch], bff = bg[64+ch], bo = bg[128+ch], bgv = bg[192+ch];
    #pragma unroll
    for (int rr = 0; rr < 8; rr++){
      int py = ty0 + rh*8 + rr, px = tx0 + ln;
      size_t pidx = ((size_t)(b*64 + ch))*NP + (size_t)py*P + px;
      f32x4 a = acc[mf][rr];
      float cv = sigmoidf_(a[1]+bff)*c0[pidx] + sigmoidf_(a[0]+bi)*tanhf(a[3]+bgv);
      float hv = sigmoidf_(a[2]+bo)*tanhf(cv);
      outh[pidx] = hv;
      outc[pidx] = cv;
    }
  }
}

extern "C" void kernel_launch(void* const* d_in, const int* in_sizes, int n_in,
                              void* d_out, int out_size, void* d_ws, size_t ws_size,
                              hipStream_t stream) {
  const float* x      = (const float*)d_in[0];
  const float* h0     = (const float*)d_in[1];
  const float* c0     = (const float*)d_in[2];
  const float* w_off1 = (const float*)d_in[3];
  const float* b_off1 = (const float*)d_in[4];
  const float* w1     = (const float*)d_in[5];
  const float* g1     = (const float*)d_in[6];
  const float* be1    = (const float*)d_in[7];
  const float* w_off2 = (const float*)d_in[8];
  const float* b_off2 = (const float*)d_in[9];
  const float* w2     = (const float*)d_in[10];
  const float* g2     = (const float*)d_in[11];
  const float* be2    = (const float*)d_in[12];
  const float* wg     = (const float*)d_in[13];
  const float* bg     = (const float*)d_in[14];

  float* ws    = (float*)d_ws;
  float* y2    = ws;                          // 4194304
  short* xh    = (short*)(ws + 4194304);      // 8388608 shorts = 4194304 floats
  float* xpcl  = ws + 4194304;                // 2097152 (dead before xh written)
  float* off   = ws + 4194304 + 2097152;      // 1179648 (dead before xh written)
  float* y1    = ws + 4194304 + 3276800;      // 4194304 (dead before xh tail written)
  float* part  = ws + 11665408;               // 8192
  float* stats = ws + 11673600;               // 128
  short* wT    = (short*)(ws + 11673728);     // 294912
  short* wd1T  = wT + 294912;                 // 18432
  short* wd2T  = wd1T + 18432;                // 36864
  short* woT1  = wd2T + 36864;                // 9216
  short* woT2  = woT1 + 9216;                 // 18432

  (void)hipFuncSetAttribute((const void*)gates_mfma_k,
                            hipFuncAttributeMaxDynamicSharedMemorySize, 148480);

  maxpool_cl_k<<<dim3((BATCH*NP + 255)/256), dim3(256), 0, stream>>>(x, xpcl);
  wprep_all_k<<<dim3((377856 + 255)/256), dim3(256), 0, stream>>>(
      wg, w1, w2, w_off1, w_off2, wT, wd1T, wd2T, woT1, woT2);

  offconv_mfma_k<32><<<dim3(128, BATCH), dim3(256), 0, stream>>>(xpcl, woT1, b_off1, off);
  deform_mfma_k<32><<<dim3(256, BATCH), dim3(256), 0, stream>>>(xpcl, off, wd1T, y1);
  bnsum_k<<<dim3(64), dim3(256), 0, stream>>>(y1, part);
  bnfinal_k<<<dim3(1), dim3(64), 0, stream>>>(part, g1, be1, stats);
  bnapply_cl_k<<<dim3((BATCH*NP*16 + 255)/256), dim3(256), 0, stream>>>(y1, stats);

  offconv_mfma_k<64><<<dim3(128, BATCH), dim3(256), 0, stream>>>(y1, woT2, b_off2, off);
  deform_mfma_k<64><<<dim3(256, BATCH), dim3(256), 0, stream>>>(y1, off, wd2T, y2);
  h2cl_k<<<dim3(NP/64, BATCH), dim3(256), 0, stream>>>(h0, xh);
  bnsum_k<<<dim3(64), dim3(256), 0, stream>>>(y2, part);
  bnfinal_k<<<dim3(1), dim3(64), 0, stream>>>(part, g2, be2, stats);
  bnapply_bf16_k<<<dim3((BATCH*NP*8 + 255)/256), dim3(256), 0, stream>>>(y2, stats, xh);

  float* outh = (float*)d_out;
  float* outc = outh + (size_t)BATCH*64*NP;
  gates_mfma_k<<<dim3(64, BATCH), dim3(512), 148480, stream>>>(xh, c0, wT, bg, outh, outc);
}